// Round 13
// baseline (914.428 us; speedup 1.0000x reference)
//
#include <hip/hip_runtime.h>
#include <math.h>

#define HID 128
#define DEPTH 4
#define PSPLIT 16
#define SMAXB 40

typedef _Float16 half8 __attribute__((ext_vector_type(8)));
typedef float f4 __attribute__((ext_vector_type(4)));

// ---------------------------------------------------------------- W split+transpose (once per launch)
__global__ void k_wsplit(const float* __restrict__ fkw, _Float16* __restrict__ whi,
                         _Float16* __restrict__ wlo) {
    __shared__ float sh[64][65];
    int bid = blockIdx.x;           // 4 layers * 16 kblk * 2 nblk = 128 blocks
    int l = bid >> 5; int r = bid & 31; int kb = r >> 1; int nbk = r & 1;
    const float* W = fkw + (size_t)l * 131072;
    _Float16* Hl = whi + (size_t)l * 131072;
    _Float16* Ll = wlo + (size_t)l * 131072;
    int k0 = kb * 64, n0 = nbk * 64;
    for (int i = threadIdx.x; i < 4096; i += 256) {
        int kk = i >> 6, nn = i & 63;
        sh[kk][nn] = W[(k0 + kk) * HID + n0 + nn];
    }
    __syncthreads();
    for (int i = threadIdx.x; i < 4096; i += 256) {
        int nn = i >> 6, kk = i & 63;
        float w = sh[kk][nn];
        _Float16 hi = (_Float16)w;
        _Float16 lo = (_Float16)((w - (float)hi) * 2048.f);
        Hl[(n0 + nn) * 1024 + k0 + kk] = hi;
        Ll[(n0 + nn) * 1024 + k0 + kk] = lo;
    }
}

// lin_w split+transpose: B[c'][k], c' in 0..255 (Wd||Ws), k in 0..127.
__global__ void k_wsplit2(const float* __restrict__ linw, _Float16* __restrict__ lwhi,
                          _Float16* __restrict__ lwlo) {
    __shared__ float sh[64][65];
    int bid = blockIdx.x;           // 4 layers * 4 cblk * 2 kblk = 32 blocks
    int l = bid >> 3; int r = bid & 7; int cb = r >> 1; int kb = r & 1;
    const float* W = linw + (size_t)l * 259 * HID;
    int c0 = cb * 64, k0 = kb * 64;
    const float* base = W + (size_t)((c0 >= 128) ? 128 : 0) * HID + (c0 & 127);
    for (int i = threadIdx.x; i < 4096; i += 256) {
        int kk = i >> 6, cc = i & 63;
        sh[kk][cc] = base[(size_t)(k0 + kk) * HID + cc];
    }
    __syncthreads();
    _Float16* Hl = lwhi + (size_t)l * 32768;
    _Float16* Ll = lwlo + (size_t)l * 32768;
    for (int i = threadIdx.x; i < 4096; i += 256) {
        int cc = i >> 6, kk = i & 63;
        float w = sh[kk][cc];
        _Float16 hi = (_Float16)w;
        _Float16 lo = (_Float16)((w - (float)hi) * 2048.f);
        Hl[(size_t)(c0 + cc) * 128 + k0 + kk] = hi;
        Ll[(size_t)(c0 + cc) * 128 + k0 + kk] = lo;
    }
}

// ---------------------------------------------------------------- CSR build
__global__ void k_hist(const int* __restrict__ dst, int* __restrict__ deg, int E) {
    int e = blockIdx.x * 256 + threadIdx.x;
    if (e < E) atomicAdd(&deg[dst[e]], 1);
}

__global__ void k_scan_a(const int* __restrict__ deg, int* __restrict__ bsum, int N) {
    __shared__ int sh[256];
    int i = blockIdx.x * 256 + threadIdx.x;
    sh[threadIdx.x] = (i < N) ? deg[i] : 0;
    __syncthreads();
    for (int off = 128; off > 0; off >>= 1) {
        if (threadIdx.x < (unsigned)off) sh[threadIdx.x] += sh[threadIdx.x + off];
        __syncthreads();
    }
    if (threadIdx.x == 0) bsum[blockIdx.x] = sh[0];
}

__global__ void k_scan_b(int* __restrict__ bsum, int nb) {
    __shared__ int sh[256];
    int v = (threadIdx.x < (unsigned)nb) ? bsum[threadIdx.x] : 0;
    sh[threadIdx.x] = v;
    __syncthreads();
    for (int off = 1; off < 256; off <<= 1) {
        int add = (threadIdx.x >= (unsigned)off) ? sh[threadIdx.x - off] : 0;
        __syncthreads();
        sh[threadIdx.x] += add;
        __syncthreads();
    }
    if (threadIdx.x < (unsigned)nb) bsum[threadIdx.x] = sh[threadIdx.x] - v;
}

__global__ void k_scan_c(const int* __restrict__ deg, const int* __restrict__ bsum,
                         int* __restrict__ offs, int* __restrict__ cursor, int N) {
    __shared__ int sh[256];
    int i = blockIdx.x * 256 + threadIdx.x;
    int v = (i < N) ? deg[i] : 0;
    sh[threadIdx.x] = v;
    __syncthreads();
    for (int off = 1; off < 256; off <<= 1) {
        int add = (threadIdx.x >= (unsigned)off) ? sh[threadIdx.x - off] : 0;
        __syncthreads();
        sh[threadIdx.x] += add;
        __syncthreads();
    }
    int ex = bsum[blockIdx.x] + sh[threadIdx.x] - v;
    if (i < N) { offs[i] = ex; cursor[i] = ex; }
    if (i == N - 1) offs[N] = ex + v;
}

__global__ void k_scatter(const int* __restrict__ src, const int* __restrict__ dst,
                          const float* __restrict__ ea, int* cursor,
                          int* __restrict__ srco, float4* __restrict__ ea3o, int E) {
    int e = blockIdx.x * 256 + threadIdx.x;
    if (e < E) {
        int d = dst[e];
        int p = atomicAdd(&cursor[d], 1);
        srco[p] = src[e];
        float4 q;
        q.x = ea[e * 3 + 0]; q.y = ea[e * 3 + 1]; q.z = ea[e * 3 + 2]; q.w = 0.f;
        ea3o[p] = q;
    }
}

__global__ void k_bstart(const int* __restrict__ batch, int* __restrict__ boffs, int N, int B) {
    int n = blockIdx.x * 256 + threadIdx.x;
    if (n >= N) return;
    int b1 = batch[n];
    if (n == 0) for (int b = 0; b <= b1; ++b) boffs[b] = 0;
    int b2 = (n + 1 < N) ? batch[n + 1] : B;
    for (int b = b1 + 1; b <= b2; ++b) boffs[b] = n + 1;
}

// ---------------------------------------------------------------- merged MFMA dispatch: fk blocks [0,FKB) + nlgemm blocks [FKB,FKB+NLB)
#define FK_MT 64
__global__ __launch_bounds__(512, 4) void k_gemms(const float* __restrict__ hsrc,
        const float* __restrict__ x, const float* __restrict__ nw, const float* __restrict__ nbv,
        const double* __restrict__ bnst, const float* __restrict__ bng, const float* __restrict__ bnb,
        int mode,
        const _Float16* __restrict__ whi, const _Float16* __restrict__ wlo,
        float* __restrict__ q0, float* __restrict__ q1,
        float* __restrict__ p2, float* __restrict__ p3,
        const _Float16* __restrict__ lwhi, const _Float16* __restrict__ lwlo,
        const float* __restrict__ linb,
        const float* __restrict__ attw, const float* __restrict__ attb,
        float* __restrict__ A1, float* __restrict__ A2,
        float* __restrict__ a1, float* __restrict__ a2,
        int FKB, int N) {
    __shared__ _Float16 ahi[FK_MT * 256];
    __shared__ _Float16 alo[FK_MT * 256];
    __shared__ float s_sc[128], s_sh[128];
    int tid = threadIdx.x;
    if (mode == 1) {
        if (tid < 128) {
            double invN = 1.0 / (double)N;
            float mu = (float)(bnst[tid] * invN);
            float var = (float)(bnst[128 + tid] * invN) - mu * mu;
            float inv = 1.f / sqrtf(var + 1e-5f);
            float sc = bng[tid] * inv;
            s_sc[tid] = sc;
            s_sh[tid] = bnb[tid] - mu * sc;
        }
        __syncthreads();
    }
    if (blockIdx.x < (unsigned)FKB) {
        // ---------------- FK body (R12 MFMA core verbatim, R19 staging)
        int bx = blockIdx.x;
        int nb = (bx >> 2) * FK_MT;
        int ks = bx & 3;
        int kbase = ks * 256;
        int fr0 = kbase >> 7;
        {
            int row = tid >> 3;          // 0..63
            int o8 = tid & 7;
            int gn = nb + row;
            int rc = (gn < N) ? gn : (N - 1);
            float hv[2][8];
            if (mode == 0) {
                float4 xr = *(const float4*)&x[(size_t)rc * 4];
#pragma unroll
                for (int s = 0; s < 2; ++s)
#pragma unroll
                    for (int j = 0; j < 8; ++j) {
                        int c = s * 64 + o8 * 8 + j;
                        hv[s][j] = nbv[c] + xr.x * nw[c] + xr.y * nw[HID + c]
                                  + xr.z * nw[2 * HID + c] + xr.w * nw[3 * HID + c];
                    }
            } else {
                const float* hp = hsrc + (size_t)rc * HID + o8 * 8;
                *(float4*)&hv[0][0] = *(const float4*)hp;
                *(float4*)&hv[0][4] = *(const float4*)(hp + 4);
                *(float4*)&hv[1][0] = *(const float4*)(hp + 64);
                *(float4*)&hv[1][4] = *(const float4*)(hp + 68);
#pragma unroll
                for (int s = 0; s < 2; ++s)
#pragma unroll
                    for (int j = 0; j < 8; ++j) {
                        int c = s * 64 + o8 * 8 + j;
                        hv[s][j] = fmaxf(hv[s][j] * s_sc[c] + s_sh[c], 0.f);
                    }
            }
            int rs = row & 7;
#pragma unroll
            for (int g = 0; g < 2; ++g) {
                float freqf = 6.2831853f * (float)(fr0 + g + 1);
#pragma unroll
                for (int s = 0; s < 2; ++s) {
                    half8 vh, vl;
#pragma unroll
                    for (int j = 0; j < 8; ++j) {
                        float ang = freqf * hv[s][j] + 0.78539816f;
                        float a = 1.41421356f * __sinf(ang);
                        _Float16 hi = (_Float16)a;
                        vh[j] = hi;
                        vl[j] = (_Float16)((a - (float)hi) * 2048.f);
                    }
                    int oct = (g * 16 + s * 8 + o8) ^ rs;   // XOR bank swizzle
                    *(half8*)&ahi[row * 256 + oct * 8] = vh;
                    *(half8*)&alo[row * 256 + oct * 8] = vl;
                }
            }
        }
        __syncthreads();
        int lane = tid & 63, wv = tid >> 6;
        int quad = lane >> 4, l16 = lane & 15;
        int n0w = wv * 16;
        f4 acc0[4], accL[4];
#pragma unroll
        for (int mi = 0; mi < 4; ++mi) { acc0[mi] = (f4)(0.f); accL[mi] = (f4)(0.f); }
        const _Float16* bhp = whi + (size_t)(n0w + l16) * 1024 + kbase + quad * 8;
        const _Float16* blp = wlo + (size_t)(n0w + l16) * 1024 + kbase + quad * 8;
        int rs16 = (l16 & 7) << 3;
#pragma unroll 2
        for (int step = 0; step < 8; ++step) {
            int ka = (step * 32 + quad * 8) ^ rs16;
            int ko = step * 32;
            half8 bh = *(const half8*)(bhp + ko);
            half8 bl = *(const half8*)(blp + ko);
            half8 ah[4], al[4];
#pragma unroll
            for (int mi = 0; mi < 4; ++mi) {
                ah[mi] = *(const half8*)&ahi[(l16 + mi * 16) * 256 + ka];
                al[mi] = *(const half8*)&alo[(l16 + mi * 16) * 256 + ka];
            }
#pragma unroll
            for (int mi = 0; mi < 4; ++mi) {
                acc0[mi] = __builtin_amdgcn_mfma_f32_16x16x32_f16(ah[mi], bh, acc0[mi], 0, 0, 0);
                accL[mi] = __builtin_amdgcn_mfma_f32_16x16x32_f16(ah[mi], bl, accL[mi], 0, 0, 0);
                accL[mi] = __builtin_amdgcn_mfma_f32_16x16x32_f16(al[mi], bh, accL[mi], 0, 0, 0);
            }
        }
        float* p = (ks == 0) ? q0 : (ks == 1) ? q1 : (ks == 2) ? p2 : p3;
        const float inv = 1.0f / 2048.0f;
#pragma unroll
        for (int mi = 0; mi < 4; ++mi)
#pragma unroll
            for (int r = 0; r < 4; ++r) {
                int gn = nb + mi * 16 + quad * 4 + r;
                if (gn < N)
                    p[gn * HID + n0w + l16] = acc0[mi][r] + accL[mi][r] * inv;
            }
    } else {
        // ---------------- nlgemm body (R19 verbatim; uses prefix of ahi/alo)
        int nb = (blockIdx.x - FKB) * 32;
        {
            int row = tid >> 4;          // 0..31
            int o16 = tid & 15;
            int gn = nb + row;
            int rc = (gn < N) ? gn : (N - 1);
            float hv[8];
            if (mode == 0) {
                float4 xr = *(const float4*)&x[(size_t)rc * 4];
#pragma unroll
                for (int j = 0; j < 8; ++j) {
                    int c = o16 * 8 + j;
                    hv[j] = nbv[c] + xr.x * nw[c] + xr.y * nw[HID + c]
                           + xr.z * nw[2 * HID + c] + xr.w * nw[3 * HID + c];
                }
            } else {
                const float* hp = hsrc + (size_t)rc * HID + o16 * 8;
                *(float4*)&hv[0] = *(const float4*)hp;
                *(float4*)&hv[4] = *(const float4*)(hp + 4);
#pragma unroll
                for (int j = 0; j < 8; ++j) {
                    int c = o16 * 8 + j;
                    hv[j] = fmaxf(hv[j] * s_sc[c] + s_sh[c], 0.f);
                }
            }
            float p1 = 0.f, p2d = 0.f;
#pragma unroll
            for (int j = 0; j < 8; ++j) {
                int k = o16 * 8 + j;
                p1 += hv[j] * attw[k];
                p2d += hv[j] * attw[128 + k];
            }
            for (int off = 8; off > 0; off >>= 1) {
                p1 += __shfl_down(p1, off, 16);
                p2d += __shfl_down(p2d, off, 16);
            }
            if (o16 == 0 && gn < N) {
                a1[gn] = p1 + attb[0];
                a2[gn] = p2d;
            }
            int rs = row & 7;
            half8 vh, vl;
#pragma unroll
            for (int j = 0; j < 8; ++j) {
                float a = hv[j];
                _Float16 hi = (_Float16)a;
                vh[j] = hi;
                vl[j] = (_Float16)((a - (float)hi) * 2048.f);
            }
            int oct = o16 ^ rs;
            *(half8*)&ahi[row * 128 + oct * 8] = vh;
            *(half8*)&alo[row * 128 + oct * 8] = vl;
        }
        __syncthreads();
        int lane = tid & 63, wv = tid >> 6;
        int quad = lane >> 4, l16 = lane & 15;
        int n0 = wv * 32;
        f4 acc0[2][2], accL[2][2];
#pragma unroll
        for (int mi = 0; mi < 2; ++mi)
#pragma unroll
            for (int ni = 0; ni < 2; ++ni) { acc0[mi][ni] = (f4)(0.f); accL[mi][ni] = (f4)(0.f); }
        const _Float16* bhp0 = lwhi + (size_t)(n0 + l16) * 128 + quad * 8;
        const _Float16* bhp1 = lwhi + (size_t)(n0 + 16 + l16) * 128 + quad * 8;
        const _Float16* blp0 = lwlo + (size_t)(n0 + l16) * 128 + quad * 8;
        const _Float16* blp1 = lwlo + (size_t)(n0 + 16 + l16) * 128 + quad * 8;
        int rs16 = (l16 & 7) << 3;
#pragma unroll
        for (int step = 0; step < 4; ++step) {
            int ka = (step * 32 + quad * 8) ^ rs16;
            int ko = step * 32;
            half8 bh0 = *(const half8*)(bhp0 + ko);
            half8 bh1 = *(const half8*)(bhp1 + ko);
            half8 bl0 = *(const half8*)(blp0 + ko);
            half8 bl1 = *(const half8*)(blp1 + ko);
            half8 ah[2], al[2];
#pragma unroll
            for (int mi = 0; mi < 2; ++mi) {
                ah[mi] = *(const half8*)&ahi[(l16 + mi * 16) * 128 + ka];
                al[mi] = *(const half8*)&alo[(l16 + mi * 16) * 128 + ka];
            }
#pragma unroll
            for (int mi = 0; mi < 2; ++mi) {
                acc0[mi][0] = __builtin_amdgcn_mfma_f32_16x16x32_f16(ah[mi], bh0, acc0[mi][0], 0, 0, 0);
                acc0[mi][1] = __builtin_amdgcn_mfma_f32_16x16x32_f16(ah[mi], bh1, acc0[mi][1], 0, 0, 0);
                accL[mi][0] = __builtin_amdgcn_mfma_f32_16x16x32_f16(ah[mi], bl0, accL[mi][0], 0, 0, 0);
                accL[mi][1] = __builtin_amdgcn_mfma_f32_16x16x32_f16(ah[mi], bl1, accL[mi][1], 0, 0, 0);
                accL[mi][0] = __builtin_amdgcn_mfma_f32_16x16x32_f16(al[mi], bh0, accL[mi][0], 0, 0, 0);
                accL[mi][1] = __builtin_amdgcn_mfma_f32_16x16x32_f16(al[mi], bh1, accL[mi][1], 0, 0, 0);
            }
        }
        const float inv = 1.0f / 2048.0f;
#pragma unroll
        for (int mi = 0; mi < 2; ++mi)
#pragma unroll
            for (int ni = 0; ni < 2; ++ni)
#pragma unroll
                for (int r = 0; r < 4; ++r) {
                    int gn = nb + mi * 16 + quad * 4 + r;
                    if (gn >= N) continue;
                    int cp = n0 + ni * 16 + l16;
                    float val = acc0[mi][ni][r] + accL[mi][ni][r] * inv;
                    if (cp < 128) A1[(size_t)gn * HID + cp] = val + linb[cp];
                    else          A2[(size_t)gn * HID + cp - 128] = val;
                }
    }
}

// ---------------------------------------------------------------- edge conv (CSR)
// R23 = R21 k_edge (4 nodes x 2 slots x 32 lanes, fused FK-partial + bias sum)
// + fused BN stats: per-block 4-node column reduce in LDS, then 256 double
// atomicAdds into the per-layer stats slice. Removes the k_bn_stats dispatch.
__global__ __launch_bounds__(256) void k_edge(const float* __restrict__ A1,
        const float* __restrict__ A2, const float* __restrict__ a1,
        const float* __restrict__ a2, const int* __restrict__ srco,
        const float4* __restrict__ ea3o, const int* __restrict__ offs,
        const float* __restrict__ linw3, const float* __restrict__ attw3,
        const float* __restrict__ q0, const float* __restrict__ q1,
        const float* __restrict__ p2s, const float* __restrict__ p3s,
        const float* __restrict__ fkb,
        float* __restrict__ hsum, double* __restrict__ stats, int N) {
    __shared__ float part[4][HID + 4];
    __shared__ float spart[4][HID];
    int tid = threadIdx.x;
    int nl = tid >> 6;               // node-local 0..3
    int slot = (tid >> 5) & 1;       // 2 slots
    int lane32 = tid & 31;
    int n = blockIdx.x * 4 + nl;
    int c4 = lane32 * 4;
    float4 w0v = *(const float4*)&linw3[c4];
    float4 w1v = *(const float4*)&linw3[HID + c4];
    float4 w2v = *(const float4*)&linw3[2 * HID + c4];
    float aw0 = attw3[0], aw1 = attw3[1], aw2 = attw3[2];
    float a1n = 0.f;
    float4 A1v; A1v.x = A1v.y = A1v.z = A1v.w = 0.f;
    int s0 = 0, s1 = 0;
    if (n < N) {
        a1n = a1[n];
        A1v = *(const float4*)&A1[(size_t)n * HID + c4];
        s0 = offs[n]; s1 = offs[n + 1];
    }
    float4 acc; acc.x = acc.y = acc.z = acc.w = 0.f;
    for (int idx = s0 + slot; idx < s1; idx += 2) {
        int s = srco[idx];
        float4 q = ea3o[idx];
        float logit = a1n + a2[s] + q.x * aw0 + q.y * aw1 + q.z * aw2;
        float al = 1.f / (1.f + __expf(-logit));
        float4 a2v = *(const float4*)&A2[(size_t)s * HID + c4];
        float4 pre;
        pre.x = A1v.x + a2v.x + q.x * w0v.x + q.y * w1v.x + q.z * w2v.x;
        pre.y = A1v.y + a2v.y + q.x * w0v.y + q.y * w1v.y + q.z * w2v.y;
        pre.z = A1v.z + a2v.z + q.x * w0v.z + q.y * w1v.z + q.z * w2v.z;
        pre.w = A1v.w + a2v.w + q.x * w0v.w + q.y * w1v.w + q.z * w2v.w;
        acc.x += al * pre.x; acc.y += al * pre.y;
        acc.z += al * pre.z; acc.w += al * pre.w;
    }
    if (slot == 1) *(float4*)&part[nl][c4] = acc;
    __syncthreads();
    if (slot == 0) {
        if (n < N) {
            float4 r = *(const float4*)&part[nl][c4];
            float4 p;
            p.x = acc.x + r.x; p.y = acc.y + r.y;
            p.z = acc.z + r.z; p.w = acc.w + r.w;
            size_t idx = (size_t)n * HID + c4;
            float4 b0 = *(const float4*)&q0[idx];
            float4 b1 = *(const float4*)&q1[idx];
            float4 b2 = *(const float4*)&p2s[idx];
            float4 b3 = *(const float4*)&p3s[idx];
            float4 bias = *(const float4*)&fkb[c4];
            p.x = p.x + b0.x + b1.x + b2.x + b3.x + bias.x;
            p.y = p.y + b0.y + b1.y + b2.y + b3.y + bias.y;
            p.z = p.z + b0.z + b1.z + b2.z + b3.z + bias.z;
            p.w = p.w + b0.w + b1.w + b2.w + b3.w + bias.w;
            *(float4*)&hsum[idx] = p;
            *(float4*)&spart[nl][c4] = p;
        } else {
            float4 z; z.x = z.y = z.z = z.w = 0.f;
            *(float4*)&spart[nl][c4] = z;
        }
    }
    __syncthreads();
    if (tid < 128) {
        int c = tid;
        float v0 = spart[0][c], v1 = spart[1][c], v2 = spart[2][c], v3 = spart[3][c];
        float t1 = v0 + v1 + v2 + v3;
        float t2 = v0 * v0 + v1 * v1 + v2 * v2 + v3 * v3;
        atomicAdd(&stats[c], (double)t1);
        atomicAdd(&stats[128 + c], (double)t2);
    }
}

// bn_final folded in; float4 per thread; pool scores (last layer only)
__global__ void k_bn_apply(const float* __restrict__ hsum, const double* __restrict__ stats,
                           const float* __restrict__ g, const float* __restrict__ b,
                           const float* __restrict__ pw, const float* __restrict__ pb,
                           float* __restrict__ h, float* __restrict__ s,
                           int do_score, int N) {
    int idx = blockIdx.x * 256 + threadIdx.x;
    int row = idx >> 5, cq = idx & 31;
    int c4 = cq * 4;
    int valid = row < N;
    double invN = 1.0 / (double)N;
    float p = 0.f;
    if (valid) {
        float4 hv = *(const float4*)&hsum[(size_t)row * HID + c4];
        float vin[4] = {hv.x, hv.y, hv.z, hv.w};
        float4 ov;
        float* po = &ov.x;
#pragma unroll
        for (int j = 0; j < 4; ++j) {
            int c = c4 + j;
            float mu = (float)(stats[c] * invN);
            float var = (float)(stats[128 + c] * invN) - mu * mu;
            float inv = 1.f / sqrtf(var + 1e-5f);
            float sc = g[c] * inv;
            float sh = b[c] - mu * sc;
            float oo = fmaxf(vin[j] * sc + sh, 0.f);
            po[j] = oo;
            if (do_score) p += oo * pw[c];
        }
        *(float4*)&h[(size_t)row * HID + c4] = ov;
    }
    if (do_score) {
        for (int off = 16; off > 0; off >>= 1) p += __shfl_down(p, off, 32);
        if ((threadIdx.x & 31) == 0 && valid) s[row] = p + pb[0];
    }
}

// ---------------------------------------------------------------- softmax partials
__global__ void k_smax1(const float* __restrict__ s, float* __restrict__ mzp, int N) {
    __shared__ float red[256];
    float m = -INFINITY;
    for (int n = blockIdx.x * 256 + threadIdx.x; n < N; n += SMAXB * 256)
        m = fmaxf(m, s[n]);
    red[threadIdx.x] = m;
    __syncthreads();
    for (int off = 128; off > 0; off >>= 1) {
        if (threadIdx.x < (unsigned)off)
            red[threadIdx.x] = fmaxf(red[threadIdx.x], red[threadIdx.x + off]);
        __syncthreads();
    }
    m = red[0];
    __syncthreads();
    float z = 0.f;
    for (int n = blockIdx.x * 256 + threadIdx.x; n < N; n += SMAXB * 256)
        z += __expf(s[n] - m);
    red[threadIdx.x] = z;
    __syncthreads();
    for (int off = 128; off > 0; off >>= 1) {
        if (threadIdx.x < (unsigned)off) red[threadIdx.x] += red[threadIdx.x + off];
        __syncthreads();
    }
    if (threadIdx.x == 0) { mzp[blockIdx.x * 2] = m; mzp[blockIdx.x * 2 + 1] = red[0]; }
}

__device__ __forceinline__ void combine_mz(const float* mzp, float& m, float& Z) {
    m = -INFINITY;
#pragma unroll 8
    for (int i = 0; i < SMAXB; ++i) m = fmaxf(m, mzp[i * 2]);
    Z = 0.f;
#pragma unroll 8
    for (int i = 0; i < SMAXB; ++i) Z += mzp[i * 2 + 1] * __expf(mzp[i * 2] - m);
}

// ---------------------------------------------------------------- attention pool (split)
__global__ void k_pool_part(const float* __restrict__ h, const float* __restrict__ s,
                            const float* __restrict__ mzp, const int* __restrict__ boffs,
                            float* __restrict__ part) {
    int b = blockIdx.x >> 4, split = blockIdx.x & (PSPLIT - 1);
    int c = threadIdx.x & 127, half = threadIdx.x >> 7;
    float m, Z;
    combine_mz(mzp, m, Z);
    (void)Z;
    int n0 = boffs[b], n1 = boffs[b + 1];
    float acc = 0.f;
    for (int n = n0 + split * 2 + half; n < n1; n += PSPLIT * 2)
        acc += __expf(s[n] - m) * h[n * HID + c];
    __shared__ float prt[2][HID];
    prt[half][c] = acc;
    __syncthreads();
    if (half == 0) part[(size_t)(b * PSPLIT + split) * HID + c] = prt[0][c] + prt[1][c];
}

// ---------------------------------------------------------------- heads (grid = B*4; pooled computed inline from part)
__global__ __launch_bounds__(256) void k_head(const float* __restrict__ part,
                       const float* __restrict__ mzp,
                       const float* __restrict__ sg_table,
                       const int* __restrict__ space_group,
                       const float* __restrict__ hw1, const float* __restrict__ hb1,
                       const float* __restrict__ ew2, const float* __restrict__ eb2,
                       const float* __restrict__ sw2, const float* __restrict__ sb2,
                       const float* __restrict__ cw2, const float* __restrict__ cb2,
                       const float* __restrict__ mw2, const float* __restrict__ mb2,
                       float* __restrict__ out, int B) {
    __shared__ float comb[256];
    __shared__ float zred[2][128];
    __shared__ float zsh[128];
    int b = blockIdx.x >> 2, i = blockIdx.x & 3;
    int t = threadIdx.x;
    if (t < 128) {
        float m, Z;
        combine_mz(mzp, m, Z);
        float acc = 0.f;
#pragma unroll
        for (int j = 0; j < PSPLIT; ++j) acc += part[(size_t)(b * PSPLIT + j) * HID + t];
        comb[t] = acc / Z;
    } else {
        comb[t] = sg_table[space_group[b] * HID + (t - 128)];
    }
    __syncthreads();
    int half = t >> 7, tt = t & 127;
    const float* W = hw1 + ((size_t)i * 256 + half * 128) * HID;
    const float* cb = &comb[half * 128];
    float z = 0.f;
#pragma unroll 8
    for (int k = 0; k < 128; ++k) z += cb[k] * W[k * HID + tt];
    zred[half][tt] = z;
    __syncthreads();
    if (t < 128) zsh[t] = fmaxf(zred[0][t] + zred[1][t] + hb1[i * HID + t], 0.f);
    __syncthreads();
    const int od[4] = {1, 3, 7, 3};
    const int base[4] = {0, 64, 256, 704};
    const float* w2 = (i == 0) ? ew2 : (i == 1) ? sw2 : (i == 2) ? cw2 : mw2;
    const float* b2 = (i == 0) ? eb2 : (i == 1) ? sb2 : (i == 2) ? cb2 : mb2;
    int odi = od[i];
    if (t < odi) {
        float o = b2[t];
        for (int c = 0; c < HID; ++c) o += zsh[c] * w2[c * odi + t];
        out[base[i] + b * odi + t] = o;
    }
}

// ---------------------------------------------------------------- launch
extern "C" void kernel_launch(void* const* d_in, const int* in_sizes, int n_in,
                              void* d_out, int out_size, void* d_ws, size_t ws_size,
                              hipStream_t stream) {
    const float* x          = (const float*)d_in[0];
    const int*   edge_index = (const int*)d_in[1];
    const float* edge_attr  = (const float*)d_in[2];
    const int*   batch      = (const int*)d_in[3];
    const int*   space_group= (const int*)d_in[4];
    const float* node_w     = (const float*)d_in[5];
    const float* node_b     = (const float*)d_in[6];
    const float* sg_table   = (const float*)d_in[7];
    const float* lin_w      = (const float*)d_in[8];
    const float* lin_b      = (const float*)d_in[9];
    const float* att_w      = (const float*)d_in[10];
    const float* att_b      = (const float*)d_in[11];
    const float* fk_w       = (const float*)d_in[12];
    const float* fk_b       = (const float*)d_in[13];
    const float* bn_g       = (const float*)d_in[14];
    const float* bn_b       = (const float*)d_in[15];
    const float* pool_w     = (const float*)d_in[16];
    const float* pool_b     = (const float*)d_in[17];
    const float* head_w1    = (const float*)d_in[18];
    const float* head_b1    = (const float*)d_in[19];
    const float* ew2 = (const float*)d_in[20]; const float* eb2 = (const float*)d_in[21];
    const float* sw2 = (const float*)d_in[22]; const float* sb2 = (const float*)d_in[23];
    const float* cw2 = (const float*)d_in[24]; const float* cb2 = (const float*)d_in[25];
    const float* mw2 = (const float*)d_in[26]; const float* mb2 = (const float*)d_in[27];
    float* out = (float*)d_out;

    const int N = in_sizes[3];
    const int E = in_sizes[1] / 2;
    const int B = in_sizes[4];
    const int* src = edge_index;
    const int* dst = edge_index + E;

    char* w = (char*)d_ws;
    auto alloc = [&](size_t bytes) { char* p = w; w += (bytes + 255) & ~(size_t)255; return p; };
    float*  h      = (float*)alloc((size_t)N * HID * 4);   // final BN'd h (layer 3)
    float*  A1     = (float*)alloc((size_t)N * HID * 4);   // nlgemm out d-half
    float*  A2     = (float*)alloc((size_t)N * HID * 4);   // nlgemm out s-half
    float*  q0     = (float*)alloc((size_t)N * HID * 4);   // FK partial 0
    float*  q1     = (float*)alloc((size_t)N * HID * 4);   // FK partial 1
    float*  p2     = (float*)alloc((size_t)N * HID * 4);   // FK partial 2
    float*  p3     = (float*)alloc((size_t)N * HID * 4);   // FK partial 3
    float*  hcv0   = (float*)alloc((size_t)N * HID * 4);   // pre-BN sum ping
    float*  hcv1   = (float*)alloc((size_t)N * HID * 4);   // pre-BN sum pong
    float*  a1     = (float*)alloc((size_t)N * 4);
    float*  a2     = (float*)alloc((size_t)N * 4);
    float*  sbuf   = (float*)alloc((size_t)N * 4);
    int*    deg    = (int*)alloc((size_t)N * 4);
    int*    cursor = (int*)alloc((size_t)N * 4);
    int*    offs   = (int*)alloc((size_t)(N + 1) * 4);
    int*    srco   = (int*)alloc((size_t)E * 4);
    float4* ea3o   = (float4*)alloc((size_t)E * 16);
    _Float16* whi  = (_Float16*)alloc((size_t)DEPTH * 1024 * HID * 2);
    _Float16* wlo  = (_Float16*)alloc((size_t)DEPTH * 1024 * HID * 2);
    _Float16* lwhi = (_Float16*)alloc((size_t)DEPTH * 256 * HID * 2);
    _Float16* lwlo = (_Float16*)alloc((size_t)DEPTH * 256 * HID * 2);
    int*    bsum   = (int*)alloc(256 * 4);
    int*    boffs  = (int*)alloc((size_t)(B + 1) * 4);
    double* stats  = (double*)alloc((size_t)DEPTH * 256 * 8);
    float*  mzp    = (float*)alloc(SMAXB * 2 * 4);
    float*  part   = (float*)alloc((size_t)B * PSPLIT * HID * 4);

    const int nchunk = (N + 255) / 256;
    const int echunk = (E + 255) / 256;
    const int FKB = ((N + FK_MT - 1) / FK_MT) * 4;
    const int NLB = (N + 31) / 32;

    // one-time per launch: W splits + CSR build + stats zero
    k_wsplit<<<128, 256, 0, stream>>>(fk_w, whi, wlo);
    k_wsplit2<<<32, 256, 0, stream>>>(lin_w, lwhi, lwlo);
    hipMemsetAsync(deg, 0, (size_t)N * 4, stream);
    hipMemsetAsync(stats, 0, (size_t)DEPTH * 256 * 8, stream);
    k_hist<<<echunk, 256, 0, stream>>>(dst, deg, E);
    k_scan_a<<<nchunk, 256, 0, stream>>>(deg, bsum, N);
    k_scan_b<<<1, 256, 0, stream>>>(bsum, nchunk);
    k_scan_c<<<nchunk, 256, 0, stream>>>(deg, bsum, offs, cursor, N);
    k_scatter<<<echunk, 256, 0, stream>>>(src, dst, edge_attr, cursor, srco, ea3o, E);
    k_bstart<<<nchunk, 256, 0, stream>>>(batch, boffs, N, B);

    float* hcv[2] = {hcv0, hcv1};
    for (int l = 0; l < DEPTH; ++l) {
        const float* linw_l = lin_w + (size_t)l * 259 * HID;
        int mode = (l == 0) ? 0 : 1;
        const double* bst = (l == 0) ? (const double*)nullptr : stats + (size_t)(l - 1) * 256;
        const float* bgl = bn_g + (size_t)((l == 0) ? 0 : (l - 1)) * HID;
        const float* bbl = bn_b + (size_t)((l == 0) ? 0 : (l - 1)) * HID;
        const float* hprev = (l == 0) ? h : hcv[(l - 1) & 1];
        float* hcur = hcv[l & 1];
        k_gemms<<<FKB + NLB, 512, 0, stream>>>(
            hprev, x, node_w, node_b, bst, bgl, bbl, mode,
            whi + (size_t)l * 131072, wlo + (size_t)l * 131072, q0, q1, p2, p3,
            lwhi + (size_t)l * 32768, lwlo + (size_t)l * 32768,
            lin_b + l * HID, att_w + (size_t)l * 259, att_b + l,
            A1, A2, a1, a2, FKB, N);
        k_edge<<<(N + 3) / 4, 256, 0, stream>>>(A1, A2, a1, a2, srco, ea3o, offs,
                                      linw_l + 256 * HID, att_w + (size_t)l * 259 + 256,
                                      q0, q1, p2, p3, fk_b + l * HID,
                                      hcur, stats + (size_t)l * 256, N);
    }
    // final BN + pool scores from layer-3 pre-BN sum
    k_bn_apply<<<(N * 32 + 255) / 256, 256, 0, stream>>>(
        hcv[(DEPTH - 1) & 1], stats + (size_t)(DEPTH - 1) * 256,
        bn_g + (size_t)(DEPTH - 1) * HID, bn_b + (size_t)(DEPTH - 1) * HID,
        pool_w, pool_b, h, sbuf, 1, N);

    k_smax1<<<SMAXB, 256, 0, stream>>>(sbuf, mzp, N);
    k_pool_part<<<B * PSPLIT, 256, 0, stream>>>(h, sbuf, mzp, boffs, part);
    k_head<<<B * 4, 256, 0, stream>>>(part, mzp, sg_table, space_group, head_w1, head_b1,
                                      ew2, eb2, sw2, sb2, cw2, cb2, mw2, mb2, out, B);
}

// Round 14
// 619.475 us; speedup vs baseline: 1.4761x; 1.4761x over previous
//
#include <hip/hip_runtime.h>
#include <math.h>

#define HID 128
#define DEPTH 4
#define PSPLIT 16
#define SMAXB 40

typedef _Float16 half8 __attribute__((ext_vector_type(8)));
typedef float f4 __attribute__((ext_vector_type(4)));

// ---------------------------------------------------------------- W split+transpose (once per launch)
__global__ void k_wsplit(const float* __restrict__ fkw, _Float16* __restrict__ whi,
                         _Float16* __restrict__ wlo) {
    __shared__ float sh[64][65];
    int bid = blockIdx.x;           // 4 layers * 16 kblk * 2 nblk = 128 blocks
    int l = bid >> 5; int r = bid & 31; int kb = r >> 1; int nbk = r & 1;
    const float* W = fkw + (size_t)l * 131072;
    _Float16* Hl = whi + (size_t)l * 131072;
    _Float16* Ll = wlo + (size_t)l * 131072;
    int k0 = kb * 64, n0 = nbk * 64;
    for (int i = threadIdx.x; i < 4096; i += 256) {
        int kk = i >> 6, nn = i & 63;
        sh[kk][nn] = W[(k0 + kk) * HID + n0 + nn];
    }
    __syncthreads();
    for (int i = threadIdx.x; i < 4096; i += 256) {
        int nn = i >> 6, kk = i & 63;
        float w = sh[kk][nn];
        _Float16 hi = (_Float16)w;
        _Float16 lo = (_Float16)((w - (float)hi) * 2048.f);
        Hl[(n0 + nn) * 1024 + k0 + kk] = hi;
        Ll[(n0 + nn) * 1024 + k0 + kk] = lo;
    }
}

// lin_w split+transpose: B[c'][k], c' in 0..255 (Wd||Ws), k in 0..127.
__global__ void k_wsplit2(const float* __restrict__ linw, _Float16* __restrict__ lwhi,
                          _Float16* __restrict__ lwlo) {
    __shared__ float sh[64][65];
    int bid = blockIdx.x;           // 4 layers * 4 cblk * 2 kblk = 32 blocks
    int l = bid >> 3; int r = bid & 7; int cb = r >> 1; int kb = r & 1;
    const float* W = linw + (size_t)l * 259 * HID;
    int c0 = cb * 64, k0 = kb * 64;
    const float* base = W + (size_t)((c0 >= 128) ? 128 : 0) * HID + (c0 & 127);
    for (int i = threadIdx.x; i < 4096; i += 256) {
        int kk = i >> 6, cc = i & 63;
        sh[kk][cc] = base[(size_t)(k0 + kk) * HID + cc];
    }
    __syncthreads();
    _Float16* Hl = lwhi + (size_t)l * 32768;
    _Float16* Ll = lwlo + (size_t)l * 32768;
    for (int i = threadIdx.x; i < 4096; i += 256) {
        int cc = i >> 6, kk = i & 63;
        float w = sh[kk][cc];
        _Float16 hi = (_Float16)w;
        _Float16 lo = (_Float16)((w - (float)hi) * 2048.f);
        Hl[(size_t)(c0 + cc) * 128 + k0 + kk] = hi;
        Ll[(size_t)(c0 + cc) * 128 + k0 + kk] = lo;
    }
}

// ---------------------------------------------------------------- CSR build
__global__ void k_hist(const int* __restrict__ dst, int* __restrict__ deg, int E) {
    int e = blockIdx.x * 256 + threadIdx.x;
    if (e < E) atomicAdd(&deg[dst[e]], 1);
}

__global__ void k_scan_a(const int* __restrict__ deg, int* __restrict__ bsum, int N) {
    __shared__ int sh[256];
    int i = blockIdx.x * 256 + threadIdx.x;
    sh[threadIdx.x] = (i < N) ? deg[i] : 0;
    __syncthreads();
    for (int off = 128; off > 0; off >>= 1) {
        if (threadIdx.x < (unsigned)off) sh[threadIdx.x] += sh[threadIdx.x + off];
        __syncthreads();
    }
    if (threadIdx.x == 0) bsum[blockIdx.x] = sh[0];
}

__global__ void k_scan_b(int* __restrict__ bsum, int nb) {
    __shared__ int sh[256];
    int v = (threadIdx.x < (unsigned)nb) ? bsum[threadIdx.x] : 0;
    sh[threadIdx.x] = v;
    __syncthreads();
    for (int off = 1; off < 256; off <<= 1) {
        int add = (threadIdx.x >= (unsigned)off) ? sh[threadIdx.x - off] : 0;
        __syncthreads();
        sh[threadIdx.x] += add;
        __syncthreads();
    }
    if (threadIdx.x < (unsigned)nb) bsum[threadIdx.x] = sh[threadIdx.x] - v;
}

__global__ void k_scan_c(const int* __restrict__ deg, const int* __restrict__ bsum,
                         int* __restrict__ offs, int* __restrict__ cursor, int N) {
    __shared__ int sh[256];
    int i = blockIdx.x * 256 + threadIdx.x;
    int v = (i < N) ? deg[i] : 0;
    sh[threadIdx.x] = v;
    __syncthreads();
    for (int off = 1; off < 256; off <<= 1) {
        int add = (threadIdx.x >= (unsigned)off) ? sh[threadIdx.x - off] : 0;
        __syncthreads();
        sh[threadIdx.x] += add;
        __syncthreads();
    }
    int ex = bsum[blockIdx.x] + sh[threadIdx.x] - v;
    if (i < N) { offs[i] = ex; cursor[i] = ex; }
    if (i == N - 1) offs[N] = ex + v;
}

__global__ void k_scatter(const int* __restrict__ src, const int* __restrict__ dst,
                          const float* __restrict__ ea, int* cursor,
                          int* __restrict__ srco, float4* __restrict__ ea3o, int E) {
    int e = blockIdx.x * 256 + threadIdx.x;
    if (e < E) {
        int d = dst[e];
        int p = atomicAdd(&cursor[d], 1);
        srco[p] = src[e];
        float4 q;
        q.x = ea[e * 3 + 0]; q.y = ea[e * 3 + 1]; q.z = ea[e * 3 + 2]; q.w = 0.f;
        ea3o[p] = q;
    }
}

__global__ void k_bstart(const int* __restrict__ batch, int* __restrict__ boffs, int N, int B) {
    int n = blockIdx.x * 256 + threadIdx.x;
    if (n >= N) return;
    int b1 = batch[n];
    if (n == 0) for (int b = 0; b <= b1; ++b) boffs[b] = 0;
    int b2 = (n + 1 < N) ? batch[n + 1] : B;
    for (int b = b1 + 1; b <= b2; ++b) boffs[b] = n + 1;
}

// ---------------------------------------------------------------- merged MFMA dispatch: fk blocks [0,FKB) + nlgemm blocks [FKB,FKB+NLB)
#define FK_MT 64
__global__ __launch_bounds__(512, 4) void k_gemms(const float* __restrict__ hsrc,
        const float* __restrict__ x, const float* __restrict__ nw, const float* __restrict__ nbv,
        const double* __restrict__ bnst, const float* __restrict__ bng, const float* __restrict__ bnb,
        int mode,
        const _Float16* __restrict__ whi, const _Float16* __restrict__ wlo,
        float* __restrict__ q0, float* __restrict__ q1,
        float* __restrict__ p2, float* __restrict__ p3,
        const _Float16* __restrict__ lwhi, const _Float16* __restrict__ lwlo,
        const float* __restrict__ linb,
        const float* __restrict__ attw, const float* __restrict__ attb,
        float* __restrict__ A1, float* __restrict__ A2,
        float* __restrict__ a1, float* __restrict__ a2,
        int FKB, int N) {
    __shared__ _Float16 ahi[FK_MT * 256];
    __shared__ _Float16 alo[FK_MT * 256];
    __shared__ float s_sc[128], s_sh[128];
    int tid = threadIdx.x;
    if (mode == 1) {
        if (tid < 128) {
            double invN = 1.0 / (double)N;
            float mu = (float)(bnst[tid] * invN);
            float var = (float)(bnst[128 + tid] * invN) - mu * mu;
            float inv = 1.f / sqrtf(var + 1e-5f);
            float sc = bng[tid] * inv;
            s_sc[tid] = sc;
            s_sh[tid] = bnb[tid] - mu * sc;
        }
        __syncthreads();
    }
    if (blockIdx.x < (unsigned)FKB) {
        // ---------------- FK body (R12 MFMA core verbatim, R19 staging)
        int bx = blockIdx.x;
        int nb = (bx >> 2) * FK_MT;
        int ks = bx & 3;
        int kbase = ks * 256;
        int fr0 = kbase >> 7;
        {
            int row = tid >> 3;          // 0..63
            int o8 = tid & 7;
            int gn = nb + row;
            int rc = (gn < N) ? gn : (N - 1);
            float hv[2][8];
            if (mode == 0) {
                float4 xr = *(const float4*)&x[(size_t)rc * 4];
#pragma unroll
                for (int s = 0; s < 2; ++s)
#pragma unroll
                    for (int j = 0; j < 8; ++j) {
                        int c = s * 64 + o8 * 8 + j;
                        hv[s][j] = nbv[c] + xr.x * nw[c] + xr.y * nw[HID + c]
                                  + xr.z * nw[2 * HID + c] + xr.w * nw[3 * HID + c];
                    }
            } else {
                const float* hp = hsrc + (size_t)rc * HID + o8 * 8;
                *(float4*)&hv[0][0] = *(const float4*)hp;
                *(float4*)&hv[0][4] = *(const float4*)(hp + 4);
                *(float4*)&hv[1][0] = *(const float4*)(hp + 64);
                *(float4*)&hv[1][4] = *(const float4*)(hp + 68);
#pragma unroll
                for (int s = 0; s < 2; ++s)
#pragma unroll
                    for (int j = 0; j < 8; ++j) {
                        int c = s * 64 + o8 * 8 + j;
                        hv[s][j] = fmaxf(hv[s][j] * s_sc[c] + s_sh[c], 0.f);
                    }
            }
            int rs = row & 7;
#pragma unroll
            for (int g = 0; g < 2; ++g) {
                float freqf = 6.2831853f * (float)(fr0 + g + 1);
#pragma unroll
                for (int s = 0; s < 2; ++s) {
                    half8 vh, vl;
#pragma unroll
                    for (int j = 0; j < 8; ++j) {
                        float ang = freqf * hv[s][j] + 0.78539816f;
                        float a = 1.41421356f * __sinf(ang);
                        _Float16 hi = (_Float16)a;
                        vh[j] = hi;
                        vl[j] = (_Float16)((a - (float)hi) * 2048.f);
                    }
                    int oct = (g * 16 + s * 8 + o8) ^ rs;   // XOR bank swizzle
                    *(half8*)&ahi[row * 256 + oct * 8] = vh;
                    *(half8*)&alo[row * 256 + oct * 8] = vl;
                }
            }
        }
        __syncthreads();
        int lane = tid & 63, wv = tid >> 6;
        int quad = lane >> 4, l16 = lane & 15;
        int n0w = wv * 16;
        f4 acc0[4], accL[4];
#pragma unroll
        for (int mi = 0; mi < 4; ++mi) { acc0[mi] = (f4)(0.f); accL[mi] = (f4)(0.f); }
        const _Float16* bhp = whi + (size_t)(n0w + l16) * 1024 + kbase + quad * 8;
        const _Float16* blp = wlo + (size_t)(n0w + l16) * 1024 + kbase + quad * 8;
        int rs16 = (l16 & 7) << 3;
#pragma unroll 2
        for (int step = 0; step < 8; ++step) {
            int ka = (step * 32 + quad * 8) ^ rs16;
            int ko = step * 32;
            half8 bh = *(const half8*)(bhp + ko);
            half8 bl = *(const half8*)(blp + ko);
            half8 ah[4], al[4];
#pragma unroll
            for (int mi = 0; mi < 4; ++mi) {
                ah[mi] = *(const half8*)&ahi[(l16 + mi * 16) * 256 + ka];
                al[mi] = *(const half8*)&alo[(l16 + mi * 16) * 256 + ka];
            }
#pragma unroll
            for (int mi = 0; mi < 4; ++mi) {
                acc0[mi] = __builtin_amdgcn_mfma_f32_16x16x32_f16(ah[mi], bh, acc0[mi], 0, 0, 0);
                accL[mi] = __builtin_amdgcn_mfma_f32_16x16x32_f16(ah[mi], bl, accL[mi], 0, 0, 0);
                accL[mi] = __builtin_amdgcn_mfma_f32_16x16x32_f16(al[mi], bh, accL[mi], 0, 0, 0);
            }
        }
        float* p = (ks == 0) ? q0 : (ks == 1) ? q1 : (ks == 2) ? p2 : p3;
        const float inv = 1.0f / 2048.0f;
#pragma unroll
        for (int mi = 0; mi < 4; ++mi)
#pragma unroll
            for (int r = 0; r < 4; ++r) {
                int gn = nb + mi * 16 + quad * 4 + r;
                if (gn < N)
                    p[gn * HID + n0w + l16] = acc0[mi][r] + accL[mi][r] * inv;
            }
    } else {
        // ---------------- nlgemm body (R19 verbatim; uses prefix of ahi/alo)
        int nb = (blockIdx.x - FKB) * 32;
        {
            int row = tid >> 4;          // 0..31
            int o16 = tid & 15;
            int gn = nb + row;
            int rc = (gn < N) ? gn : (N - 1);
            float hv[8];
            if (mode == 0) {
                float4 xr = *(const float4*)&x[(size_t)rc * 4];
#pragma unroll
                for (int j = 0; j < 8; ++j) {
                    int c = o16 * 8 + j;
                    hv[j] = nbv[c] + xr.x * nw[c] + xr.y * nw[HID + c]
                           + xr.z * nw[2 * HID + c] + xr.w * nw[3 * HID + c];
                }
            } else {
                const float* hp = hsrc + (size_t)rc * HID + o16 * 8;
                *(float4*)&hv[0] = *(const float4*)hp;
                *(float4*)&hv[4] = *(const float4*)(hp + 4);
#pragma unroll
                for (int j = 0; j < 8; ++j) {
                    int c = o16 * 8 + j;
                    hv[j] = fmaxf(hv[j] * s_sc[c] + s_sh[c], 0.f);
                }
            }
            float p1 = 0.f, p2d = 0.f;
#pragma unroll
            for (int j = 0; j < 8; ++j) {
                int k = o16 * 8 + j;
                p1 += hv[j] * attw[k];
                p2d += hv[j] * attw[128 + k];
            }
            for (int off = 8; off > 0; off >>= 1) {
                p1 += __shfl_down(p1, off, 16);
                p2d += __shfl_down(p2d, off, 16);
            }
            if (o16 == 0 && gn < N) {
                a1[gn] = p1 + attb[0];
                a2[gn] = p2d;
            }
            int rs = row & 7;
            half8 vh, vl;
#pragma unroll
            for (int j = 0; j < 8; ++j) {
                float a = hv[j];
                _Float16 hi = (_Float16)a;
                vh[j] = hi;
                vl[j] = (_Float16)((a - (float)hi) * 2048.f);
            }
            int oct = o16 ^ rs;
            *(half8*)&ahi[row * 128 + oct * 8] = vh;
            *(half8*)&alo[row * 128 + oct * 8] = vl;
        }
        __syncthreads();
        int lane = tid & 63, wv = tid >> 6;
        int quad = lane >> 4, l16 = lane & 15;
        int n0 = wv * 32;
        f4 acc0[2][2], accL[2][2];
#pragma unroll
        for (int mi = 0; mi < 2; ++mi)
#pragma unroll
            for (int ni = 0; ni < 2; ++ni) { acc0[mi][ni] = (f4)(0.f); accL[mi][ni] = (f4)(0.f); }
        const _Float16* bhp0 = lwhi + (size_t)(n0 + l16) * 128 + quad * 8;
        const _Float16* bhp1 = lwhi + (size_t)(n0 + 16 + l16) * 128 + quad * 8;
        const _Float16* blp0 = lwlo + (size_t)(n0 + l16) * 128 + quad * 8;
        const _Float16* blp1 = lwlo + (size_t)(n0 + 16 + l16) * 128 + quad * 8;
        int rs16 = (l16 & 7) << 3;
#pragma unroll
        for (int step = 0; step < 4; ++step) {
            int ka = (step * 32 + quad * 8) ^ rs16;
            int ko = step * 32;
            half8 bh0 = *(const half8*)(bhp0 + ko);
            half8 bh1 = *(const half8*)(bhp1 + ko);
            half8 bl0 = *(const half8*)(blp0 + ko);
            half8 bl1 = *(const half8*)(blp1 + ko);
            half8 ah[2], al[2];
#pragma unroll
            for (int mi = 0; mi < 2; ++mi) {
                ah[mi] = *(const half8*)&ahi[(l16 + mi * 16) * 128 + ka];
                al[mi] = *(const half8*)&alo[(l16 + mi * 16) * 128 + ka];
            }
#pragma unroll
            for (int mi = 0; mi < 2; ++mi) {
                acc0[mi][0] = __builtin_amdgcn_mfma_f32_16x16x32_f16(ah[mi], bh0, acc0[mi][0], 0, 0, 0);
                acc0[mi][1] = __builtin_amdgcn_mfma_f32_16x16x32_f16(ah[mi], bh1, acc0[mi][1], 0, 0, 0);
                accL[mi][0] = __builtin_amdgcn_mfma_f32_16x16x32_f16(ah[mi], bl0, accL[mi][0], 0, 0, 0);
                accL[mi][1] = __builtin_amdgcn_mfma_f32_16x16x32_f16(ah[mi], bl1, accL[mi][1], 0, 0, 0);
                accL[mi][0] = __builtin_amdgcn_mfma_f32_16x16x32_f16(al[mi], bh0, accL[mi][0], 0, 0, 0);
                accL[mi][1] = __builtin_amdgcn_mfma_f32_16x16x32_f16(al[mi], bh1, accL[mi][1], 0, 0, 0);
            }
        }
        const float inv = 1.0f / 2048.0f;
#pragma unroll
        for (int mi = 0; mi < 2; ++mi)
#pragma unroll
            for (int ni = 0; ni < 2; ++ni)
#pragma unroll
                for (int r = 0; r < 4; ++r) {
                    int gn = nb + mi * 16 + quad * 4 + r;
                    if (gn >= N) continue;
                    int cp = n0 + ni * 16 + l16;
                    float val = acc0[mi][ni][r] + accL[mi][ni][r] * inv;
                    if (cp < 128) A1[(size_t)gn * HID + cp] = val + linb[cp];
                    else          A2[(size_t)gn * HID + cp - 128] = val;
                }
    }
}

// ---------------------------------------------------------------- edge conv (CSR)
// R24 = R21 k_edge (4 nodes x 2 slots x 32 lanes, fused FK-partial + bias
// sum, NO stats atomics — R23 showed 256-address f64 atomics serialize)
// + index/attr software prefetch: srco/ea3o for edge i+1 are loaded before
// consuming edge i, overlapping the next index fetch with the current A2
// gather. Same accumulation order -> bit-identical to R21.
__global__ __launch_bounds__(256) void k_edge(const float* __restrict__ A1,
        const float* __restrict__ A2, const float* __restrict__ a1,
        const float* __restrict__ a2, const int* __restrict__ srco,
        const float4* __restrict__ ea3o, const int* __restrict__ offs,
        const float* __restrict__ linw3, const float* __restrict__ attw3,
        const float* __restrict__ q0, const float* __restrict__ q1,
        const float* __restrict__ p2s, const float* __restrict__ p3s,
        const float* __restrict__ fkb,
        float* __restrict__ hsum, int N) {
    __shared__ float part[4][HID + 4];
    int tid = threadIdx.x;
    int nl = tid >> 6;               // node-local 0..3
    int slot = (tid >> 5) & 1;       // 2 slots
    int lane32 = tid & 31;
    int n = blockIdx.x * 4 + nl;
    int c4 = lane32 * 4;
    float4 w0v = *(const float4*)&linw3[c4];
    float4 w1v = *(const float4*)&linw3[HID + c4];
    float4 w2v = *(const float4*)&linw3[2 * HID + c4];
    float aw0 = attw3[0], aw1 = attw3[1], aw2 = attw3[2];
    float a1n = 0.f;
    float4 A1v; A1v.x = A1v.y = A1v.z = A1v.w = 0.f;
    int s0 = 0, s1 = 0;
    if (n < N) {
        a1n = a1[n];
        A1v = *(const float4*)&A1[(size_t)n * HID + c4];
        s0 = offs[n]; s1 = offs[n + 1];
    }
    float4 acc; acc.x = acc.y = acc.z = acc.w = 0.f;
    int idx = s0 + slot;
    if (idx < s1) {
        int s = srco[idx];
        float4 q = ea3o[idx];
        float a2s = a2[s];
        while (1) {
            int idx2 = idx + 2;
            int sn = 0; float4 qn; float a2n = 0.f;
            int more = idx2 < s1;
            if (more) {                      // prefetch next edge's index/attr/a2
                sn = srco[idx2];
                qn = ea3o[idx2];
                a2n = a2[sn];
            }
            float logit = a1n + a2s + q.x * aw0 + q.y * aw1 + q.z * aw2;
            float al = 1.f / (1.f + __expf(-logit));
            float4 a2v = *(const float4*)&A2[(size_t)s * HID + c4];
            float4 pre;
            pre.x = A1v.x + a2v.x + q.x * w0v.x + q.y * w1v.x + q.z * w2v.x;
            pre.y = A1v.y + a2v.y + q.x * w0v.y + q.y * w1v.y + q.z * w2v.y;
            pre.z = A1v.z + a2v.z + q.x * w0v.z + q.y * w1v.z + q.z * w2v.z;
            pre.w = A1v.w + a2v.w + q.x * w0v.w + q.y * w1v.w + q.z * w2v.w;
            acc.x += al * pre.x; acc.y += al * pre.y;
            acc.z += al * pre.z; acc.w += al * pre.w;
            if (!more) break;
            idx = idx2; s = sn; q = qn; a2s = a2n;
        }
    }
    if (slot == 1) *(float4*)&part[nl][c4] = acc;
    __syncthreads();
    if (slot == 0 && n < N) {
        float4 r = *(const float4*)&part[nl][c4];
        float4 p;
        p.x = acc.x + r.x; p.y = acc.y + r.y;
        p.z = acc.z + r.z; p.w = acc.w + r.w;
        size_t idx2 = (size_t)n * HID + c4;
        float4 b0 = *(const float4*)&q0[idx2];
        float4 b1 = *(const float4*)&q1[idx2];
        float4 b2 = *(const float4*)&p2s[idx2];
        float4 b3 = *(const float4*)&p3s[idx2];
        float4 bias = *(const float4*)&fkb[c4];
        p.x = p.x + b0.x + b1.x + b2.x + b3.x + bias.x;
        p.y = p.y + b0.y + b1.y + b2.y + b3.y + bias.y;
        p.z = p.z + b0.z + b1.z + b2.z + b3.z + bias.z;
        p.w = p.w + b0.w + b1.w + b2.w + b3.w + bias.w;
        *(float4*)&hsum[idx2] = p;
    }
}

// ---------------------------------------------------------------- batchnorm stats (single stream)
__global__ __launch_bounds__(256) void k_bn_stats(const float* __restrict__ hsum,
                           double* __restrict__ stats, int N) {
    int tid = threadIdx.x;
    int cq = tid & 31, rg = tid >> 5;
    int c4 = cq * 4;
    float s1[4] = {0, 0, 0, 0}, s2[4] = {0, 0, 0, 0};
    for (int n = blockIdx.x * 8 + rg; n < N; n += gridDim.x * 8) {
        float4 v = *(const float4*)&hsum[(size_t)n * HID + c4];
        s1[0] += v.x; s2[0] += v.x * v.x;
        s1[1] += v.y; s2[1] += v.y * v.y;
        s1[2] += v.z; s2[2] += v.z * v.z;
        s1[3] += v.w; s2[3] += v.w * v.w;
    }
#pragma unroll
    for (int j = 0; j < 4; ++j) {
        s1[j] += __shfl_down(s1[j], 32);
        s2[j] += __shfl_down(s2[j], 32);
    }
    __shared__ float sh1[4][32][4], sh2[4][32][4];
    int wv = tid >> 6, lane = tid & 63;
    if (lane < 32) {
#pragma unroll
        for (int j = 0; j < 4; ++j) { sh1[wv][lane][j] = s1[j]; sh2[wv][lane][j] = s2[j]; }
    }
    __syncthreads();
    if (tid < 128) {
        int cq2 = tid >> 2, j2 = tid & 3;
        float t1 = sh1[0][cq2][j2] + sh1[1][cq2][j2] + sh1[2][cq2][j2] + sh1[3][cq2][j2];
        float t2 = sh2[0][cq2][j2] + sh2[1][cq2][j2] + sh2[2][cq2][j2] + sh2[3][cq2][j2];
        int c = cq2 * 4 + j2;
        atomicAdd(&stats[c], (double)t1);
        atomicAdd(&stats[128 + c], (double)t2);
    }
}

// bn_final folded in; float4 per thread; pool scores (last layer only)
__global__ void k_bn_apply(const float* __restrict__ hsum, const double* __restrict__ stats,
                           const float* __restrict__ g, const float* __restrict__ b,
                           const float* __restrict__ pw, const float* __restrict__ pb,
                           float* __restrict__ h, float* __restrict__ s,
                           int do_score, int N) {
    int idx = blockIdx.x * 256 + threadIdx.x;
    int row = idx >> 5, cq = idx & 31;
    int c4 = cq * 4;
    int valid = row < N;
    double invN = 1.0 / (double)N;
    float p = 0.f;
    if (valid) {
        float4 hv = *(const float4*)&hsum[(size_t)row * HID + c4];
        float vin[4] = {hv.x, hv.y, hv.z, hv.w};
        float4 ov;
        float* po = &ov.x;
#pragma unroll
        for (int j = 0; j < 4; ++j) {
            int c = c4 + j;
            float mu = (float)(stats[c] * invN);
            float var = (float)(stats[128 + c] * invN) - mu * mu;
            float inv = 1.f / sqrtf(var + 1e-5f);
            float sc = g[c] * inv;
            float sh = b[c] - mu * sc;
            float oo = fmaxf(vin[j] * sc + sh, 0.f);
            po[j] = oo;
            if (do_score) p += oo * pw[c];
        }
        *(float4*)&h[(size_t)row * HID + c4] = ov;
    }
    if (do_score) {
        for (int off = 16; off > 0; off >>= 1) p += __shfl_down(p, off, 32);
        if ((threadIdx.x & 31) == 0 && valid) s[row] = p + pb[0];
    }
}

// ---------------------------------------------------------------- softmax partials
__global__ void k_smax1(const float* __restrict__ s, float* __restrict__ mzp, int N) {
    __shared__ float red[256];
    float m = -INFINITY;
    for (int n = blockIdx.x * 256 + threadIdx.x; n < N; n += SMAXB * 256)
        m = fmaxf(m, s[n]);
    red[threadIdx.x] = m;
    __syncthreads();
    for (int off = 128; off > 0; off >>= 1) {
        if (threadIdx.x < (unsigned)off)
            red[threadIdx.x] = fmaxf(red[threadIdx.x], red[threadIdx.x + off]);
        __syncthreads();
    }
    m = red[0];
    __syncthreads();
    float z = 0.f;
    for (int n = blockIdx.x * 256 + threadIdx.x; n < N; n += SMAXB * 256)
        z += __expf(s[n] - m);
    red[threadIdx.x] = z;
    __syncthreads();
    for (int off = 128; off > 0; off >>= 1) {
        if (threadIdx.x < (unsigned)off) red[threadIdx.x] += red[threadIdx.x + off];
        __syncthreads();
    }
    if (threadIdx.x == 0) { mzp[blockIdx.x * 2] = m; mzp[blockIdx.x * 2 + 1] = red[0]; }
}

__device__ __forceinline__ void combine_mz(const float* mzp, float& m, float& Z) {
    m = -INFINITY;
#pragma unroll 8
    for (int i = 0; i < SMAXB; ++i) m = fmaxf(m, mzp[i * 2]);
    Z = 0.f;
#pragma unroll 8
    for (int i = 0; i < SMAXB; ++i) Z += mzp[i * 2 + 1] * __expf(mzp[i * 2] - m);
}

// ---------------------------------------------------------------- attention pool (split)
__global__ void k_pool_part(const float* __restrict__ h, const float* __restrict__ s,
                            const float* __restrict__ mzp, const int* __restrict__ boffs,
                            float* __restrict__ part) {
    int b = blockIdx.x >> 4, split = blockIdx.x & (PSPLIT - 1);
    int c = threadIdx.x & 127, half = threadIdx.x >> 7;
    float m, Z;
    combine_mz(mzp, m, Z);
    (void)Z;
    int n0 = boffs[b], n1 = boffs[b + 1];
    float acc = 0.f;
    for (int n = n0 + split * 2 + half; n < n1; n += PSPLIT * 2)
        acc += __expf(s[n] - m) * h[n * HID + c];
    __shared__ float prt[2][HID];
    prt[half][c] = acc;
    __syncthreads();
    if (half == 0) part[(size_t)(b * PSPLIT + split) * HID + c] = prt[0][c] + prt[1][c];
}

// ---------------------------------------------------------------- heads (grid = B*4; pooled computed inline from part)
__global__ __launch_bounds__(256) void k_head(const float* __restrict__ part,
                       const float* __restrict__ mzp,
                       const float* __restrict__ sg_table,
                       const int* __restrict__ space_group,
                       const float* __restrict__ hw1, const float* __restrict__ hb1,
                       const float* __restrict__ ew2, const float* __restrict__ eb2,
                       const float* __restrict__ sw2, const float* __restrict__ sb2,
                       const float* __restrict__ cw2, const float* __restrict__ cb2,
                       const float* __restrict__ mw2, const float* __restrict__ mb2,
                       float* __restrict__ out, int B) {
    __shared__ float comb[256];
    __shared__ float zred[2][128];
    __shared__ float zsh[128];
    int b = blockIdx.x >> 2, i = blockIdx.x & 3;
    int t = threadIdx.x;
    if (t < 128) {
        float m, Z;
        combine_mz(mzp, m, Z);
        float acc = 0.f;
#pragma unroll
        for (int j = 0; j < PSPLIT; ++j) acc += part[(size_t)(b * PSPLIT + j) * HID + t];
        comb[t] = acc / Z;
    } else {
        comb[t] = sg_table[space_group[b] * HID + (t - 128)];
    }
    __syncthreads();
    int half = t >> 7, tt = t & 127;
    const float* W = hw1 + ((size_t)i * 256 + half * 128) * HID;
    const float* cb = &comb[half * 128];
    float z = 0.f;
#pragma unroll 8
    for (int k = 0; k < 128; ++k) z += cb[k] * W[k * HID + tt];
    zred[half][tt] = z;
    __syncthreads();
    if (t < 128) zsh[t] = fmaxf(zred[0][t] + zred[1][t] + hb1[i * HID + t], 0.f);
    __syncthreads();
    const int od[4] = {1, 3, 7, 3};
    const int base[4] = {0, 64, 256, 704};
    const float* w2 = (i == 0) ? ew2 : (i == 1) ? sw2 : (i == 2) ? cw2 : mw2;
    const float* b2 = (i == 0) ? eb2 : (i == 1) ? sb2 : (i == 2) ? cb2 : mb2;
    int odi = od[i];
    if (t < odi) {
        float o = b2[t];
        for (int c = 0; c < HID; ++c) o += zsh[c] * w2[c * odi + t];
        out[base[i] + b * odi + t] = o;
    }
}

// ---------------------------------------------------------------- launch
extern "C" void kernel_launch(void* const* d_in, const int* in_sizes, int n_in,
                              void* d_out, int out_size, void* d_ws, size_t ws_size,
                              hipStream_t stream) {
    const float* x          = (const float*)d_in[0];
    const int*   edge_index = (const int*)d_in[1];
    const float* edge_attr  = (const float*)d_in[2];
    const int*   batch      = (const int*)d_in[3];
    const int*   space_group= (const int*)d_in[4];
    const float* node_w     = (const float*)d_in[5];
    const float* node_b     = (const float*)d_in[6];
    const float* sg_table   = (const float*)d_in[7];
    const float* lin_w      = (const float*)d_in[8];
    const float* lin_b      = (const float*)d_in[9];
    const float* att_w      = (const float*)d_in[10];
    const float* att_b      = (const float*)d_in[11];
    const float* fk_w       = (const float*)d_in[12];
    const float* fk_b       = (const float*)d_in[13];
    const float* bn_g       = (const float*)d_in[14];
    const float* bn_b       = (const float*)d_in[15];
    const float* pool_w     = (const float*)d_in[16];
    const float* pool_b     = (const float*)d_in[17];
    const float* head_w1    = (const float*)d_in[18];
    const float* head_b1    = (const float*)d_in[19];
    const float* ew2 = (const float*)d_in[20]; const float* eb2 = (const float*)d_in[21];
    const float* sw2 = (const float*)d_in[22]; const float* sb2 = (const float*)d_in[23];
    const float* cw2 = (const float*)d_in[24]; const float* cb2 = (const float*)d_in[25];
    const float* mw2 = (const float*)d_in[26]; const float* mb2 = (const float*)d_in[27];
    float* out = (float*)d_out;

    const int N = in_sizes[3];
    const int E = in_sizes[1] / 2;
    const int B = in_sizes[4];
    const int* src = edge_index;
    const int* dst = edge_index + E;

    char* w = (char*)d_ws;
    auto alloc = [&](size_t bytes) { char* p = w; w += (bytes + 255) & ~(size_t)255; return p; };
    float*  h      = (float*)alloc((size_t)N * HID * 4);   // final BN'd h (layer 3)
    float*  A1     = (float*)alloc((size_t)N * HID * 4);   // nlgemm out d-half
    float*  A2     = (float*)alloc((size_t)N * HID * 4);   // nlgemm out s-half
    float*  q0     = (float*)alloc((size_t)N * HID * 4);   // FK partial 0
    float*  q1     = (float*)alloc((size_t)N * HID * 4);   // FK partial 1
    float*  p2     = (float*)alloc((size_t)N * HID * 4);   // FK partial 2
    float*  p3     = (float*)alloc((size_t)N * HID * 4);   // FK partial 3
    float*  hcv0   = (float*)alloc((size_t)N * HID * 4);   // pre-BN sum ping
    float*  hcv1   = (float*)alloc((size_t)N * HID * 4);   // pre-BN sum pong
    float*  a1     = (float*)alloc((size_t)N * 4);
    float*  a2     = (float*)alloc((size_t)N * 4);
    float*  sbuf   = (float*)alloc((size_t)N * 4);
    int*    deg    = (int*)alloc((size_t)N * 4);
    int*    cursor = (int*)alloc((size_t)N * 4);
    int*    offs   = (int*)alloc((size_t)(N + 1) * 4);
    int*    srco   = (int*)alloc((size_t)E * 4);
    float4* ea3o   = (float4*)alloc((size_t)E * 16);
    _Float16* whi  = (_Float16*)alloc((size_t)DEPTH * 1024 * HID * 2);
    _Float16* wlo  = (_Float16*)alloc((size_t)DEPTH * 1024 * HID * 2);
    _Float16* lwhi = (_Float16*)alloc((size_t)DEPTH * 256 * HID * 2);
    _Float16* lwlo = (_Float16*)alloc((size_t)DEPTH * 256 * HID * 2);
    int*    bsum   = (int*)alloc(256 * 4);
    int*    boffs  = (int*)alloc((size_t)(B + 1) * 4);
    double* stats  = (double*)alloc((size_t)DEPTH * 256 * 8);
    float*  mzp    = (float*)alloc(SMAXB * 2 * 4);
    float*  part   = (float*)alloc((size_t)B * PSPLIT * HID * 4);

    const int nchunk = (N + 255) / 256;
    const int echunk = (E + 255) / 256;
    const int FKB = ((N + FK_MT - 1) / FK_MT) * 4;
    const int NLB = (N + 31) / 32;

    // one-time per launch: W splits + CSR build + stats zero
    k_wsplit<<<128, 256, 0, stream>>>(fk_w, whi, wlo);
    k_wsplit2<<<32, 256, 0, stream>>>(lin_w, lwhi, lwlo);
    hipMemsetAsync(deg, 0, (size_t)N * 4, stream);
    hipMemsetAsync(stats, 0, (size_t)DEPTH * 256 * 8, stream);
    k_hist<<<echunk, 256, 0, stream>>>(dst, deg, E);
    k_scan_a<<<nchunk, 256, 0, stream>>>(deg, bsum, N);
    k_scan_b<<<1, 256, 0, stream>>>(bsum, nchunk);
    k_scan_c<<<nchunk, 256, 0, stream>>>(deg, bsum, offs, cursor, N);
    k_scatter<<<echunk, 256, 0, stream>>>(src, dst, edge_attr, cursor, srco, ea3o, E);
    k_bstart<<<nchunk, 256, 0, stream>>>(batch, boffs, N, B);

    float* hcv[2] = {hcv0, hcv1};
    for (int l = 0; l < DEPTH; ++l) {
        const float* linw_l = lin_w + (size_t)l * 259 * HID;
        int mode = (l == 0) ? 0 : 1;
        const double* bst = (l == 0) ? (const double*)nullptr : stats + (size_t)(l - 1) * 256;
        const float* bgl = bn_g + (size_t)((l == 0) ? 0 : (l - 1)) * HID;
        const float* bbl = bn_b + (size_t)((l == 0) ? 0 : (l - 1)) * HID;
        const float* hprev = (l == 0) ? h : hcv[(l - 1) & 1];
        float* hcur = hcv[l & 1];
        k_gemms<<<FKB + NLB, 512, 0, stream>>>(
            hprev, x, node_w, node_b, bst, bgl, bbl, mode,
            whi + (size_t)l * 131072, wlo + (size_t)l * 131072, q0, q1, p2, p3,
            lwhi + (size_t)l * 32768, lwlo + (size_t)l * 32768,
            lin_b + l * HID, att_w + (size_t)l * 259, att_b + l,
            A1, A2, a1, a2, FKB, N);
        k_edge<<<(N + 3) / 4, 256, 0, stream>>>(A1, A2, a1, a2, srco, ea3o, offs,
                                      linw_l + 256 * HID, att_w + (size_t)l * 259 + 256,
                                      q0, q1, p2, p3, fk_b + l * HID,
                                      hcur, N);
        k_bn_stats<<<320, 256, 0, stream>>>(hcur, stats + (size_t)l * 256, N);
    }
    // final BN + pool scores from layer-3 pre-BN sum
    k_bn_apply<<<(N * 32 + 255) / 256, 256, 0, stream>>>(
        hcv[(DEPTH - 1) & 1], stats + (size_t)(DEPTH - 1) * 256,
        bn_g + (size_t)(DEPTH - 1) * HID, bn_b + (size_t)(DEPTH - 1) * HID,
        pool_w, pool_b, h, sbuf, 1, N);

    k_smax1<<<SMAXB, 256, 0, stream>>>(sbuf, mzp, N);
    k_pool_part<<<B * PSPLIT, 256, 0, stream>>>(h, sbuf, mzp, boffs, part);
    k_head<<<B * 4, 256, 0, stream>>>(part, mzp, sg_table, space_group, head_w1, head_b1,
                                      ew2, eb2, sw2, sb2, cw2, cb2, mw2, mb2, out, B);
}

// Round 15
// 603.745 us; speedup vs baseline: 1.5146x; 1.0261x over previous
//
#include <hip/hip_runtime.h>
#include <math.h>

#define HID 128
#define DEPTH 4
#define PSPLIT 16
#define SMAXB 40

typedef _Float16 half8 __attribute__((ext_vector_type(8)));
typedef float f4 __attribute__((ext_vector_type(4)));

// ---------------------------------------------------------------- W split+transpose (once per launch)
__global__ void k_wsplit(const float* __restrict__ fkw, _Float16* __restrict__ whi,
                         _Float16* __restrict__ wlo) {
    __shared__ float sh[64][65];
    int bid = blockIdx.x;           // 4 layers * 16 kblk * 2 nblk = 128 blocks
    int l = bid >> 5; int r = bid & 31; int kb = r >> 1; int nbk = r & 1;
    const float* W = fkw + (size_t)l * 131072;
    _Float16* Hl = whi + (size_t)l * 131072;
    _Float16* Ll = wlo + (size_t)l * 131072;
    int k0 = kb * 64, n0 = nbk * 64;
    for (int i = threadIdx.x; i < 4096; i += 256) {
        int kk = i >> 6, nn = i & 63;
        sh[kk][nn] = W[(k0 + kk) * HID + n0 + nn];
    }
    __syncthreads();
    for (int i = threadIdx.x; i < 4096; i += 256) {
        int nn = i >> 6, kk = i & 63;
        float w = sh[kk][nn];
        _Float16 hi = (_Float16)w;
        _Float16 lo = (_Float16)((w - (float)hi) * 2048.f);
        Hl[(n0 + nn) * 1024 + k0 + kk] = hi;
        Ll[(n0 + nn) * 1024 + k0 + kk] = lo;
    }
}

// lin_w split+transpose: B[c'][k], c' in 0..255 (Wd||Ws), k in 0..127.
__global__ void k_wsplit2(const float* __restrict__ linw, _Float16* __restrict__ lwhi,
                          _Float16* __restrict__ lwlo) {
    __shared__ float sh[64][65];
    int bid = blockIdx.x;           // 4 layers * 4 cblk * 2 kblk = 32 blocks
    int l = bid >> 3; int r = bid & 7; int cb = r >> 1; int kb = r & 1;
    const float* W = linw + (size_t)l * 259 * HID;
    int c0 = cb * 64, k0 = kb * 64;
    const float* base = W + (size_t)((c0 >= 128) ? 128 : 0) * HID + (c0 & 127);
    for (int i = threadIdx.x; i < 4096; i += 256) {
        int kk = i >> 6, cc = i & 63;
        sh[kk][cc] = base[(size_t)(k0 + kk) * HID + cc];
    }
    __syncthreads();
    _Float16* Hl = lwhi + (size_t)l * 32768;
    _Float16* Ll = lwlo + (size_t)l * 32768;
    for (int i = threadIdx.x; i < 4096; i += 256) {
        int cc = i >> 6, kk = i & 63;
        float w = sh[kk][cc];
        _Float16 hi = (_Float16)w;
        _Float16 lo = (_Float16)((w - (float)hi) * 2048.f);
        Hl[(size_t)(c0 + cc) * 128 + k0 + kk] = hi;
        Ll[(size_t)(c0 + cc) * 128 + k0 + kk] = lo;
    }
}

// ---------------------------------------------------------------- CSR build
__global__ void k_hist(const int* __restrict__ dst, int* __restrict__ deg, int E) {
    int e = blockIdx.x * 256 + threadIdx.x;
    if (e < E) atomicAdd(&deg[dst[e]], 1);
}

__global__ void k_scan_a(const int* __restrict__ deg, int* __restrict__ bsum, int N) {
    __shared__ int sh[256];
    int i = blockIdx.x * 256 + threadIdx.x;
    sh[threadIdx.x] = (i < N) ? deg[i] : 0;
    __syncthreads();
    for (int off = 128; off > 0; off >>= 1) {
        if (threadIdx.x < (unsigned)off) sh[threadIdx.x] += sh[threadIdx.x + off];
        __syncthreads();
    }
    if (threadIdx.x == 0) bsum[blockIdx.x] = sh[0];
}

__global__ void k_scan_b(int* __restrict__ bsum, int nb) {
    __shared__ int sh[256];
    int v = (threadIdx.x < (unsigned)nb) ? bsum[threadIdx.x] : 0;
    sh[threadIdx.x] = v;
    __syncthreads();
    for (int off = 1; off < 256; off <<= 1) {
        int add = (threadIdx.x >= (unsigned)off) ? sh[threadIdx.x - off] : 0;
        __syncthreads();
        sh[threadIdx.x] += add;
        __syncthreads();
    }
    if (threadIdx.x < (unsigned)nb) bsum[threadIdx.x] = sh[threadIdx.x] - v;
}

__global__ void k_scan_c(const int* __restrict__ deg, const int* __restrict__ bsum,
                         int* __restrict__ offs, int* __restrict__ cursor, int N) {
    __shared__ int sh[256];
    int i = blockIdx.x * 256 + threadIdx.x;
    int v = (i < N) ? deg[i] : 0;
    sh[threadIdx.x] = v;
    __syncthreads();
    for (int off = 1; off < 256; off <<= 1) {
        int add = (threadIdx.x >= (unsigned)off) ? sh[threadIdx.x - off] : 0;
        __syncthreads();
        sh[threadIdx.x] += add;
        __syncthreads();
    }
    int ex = bsum[blockIdx.x] + sh[threadIdx.x] - v;
    if (i < N) { offs[i] = ex; cursor[i] = ex; }
    if (i == N - 1) offs[N] = ex + v;
}

__global__ void k_scatter(const int* __restrict__ src, const int* __restrict__ dst,
                          const float* __restrict__ ea, int* cursor,
                          int* __restrict__ srco, float4* __restrict__ ea3o, int E) {
    int e = blockIdx.x * 256 + threadIdx.x;
    if (e < E) {
        int d = dst[e];
        int p = atomicAdd(&cursor[d], 1);
        srco[p] = src[e];
        float4 q;
        q.x = ea[e * 3 + 0]; q.y = ea[e * 3 + 1]; q.z = ea[e * 3 + 2]; q.w = 0.f;
        ea3o[p] = q;
    }
}

__global__ void k_bstart(const int* __restrict__ batch, int* __restrict__ boffs, int N, int B) {
    int n = blockIdx.x * 256 + threadIdx.x;
    if (n >= N) return;
    int b1 = batch[n];
    if (n == 0) for (int b = 0; b <= b1; ++b) boffs[b] = 0;
    int b2 = (n + 1 < N) ? batch[n + 1] : B;
    for (int b = b1 + 1; b <= b2; ++b) boffs[b] = n + 1;
}

// ---------------------------------------------------------------- merged MFMA dispatch: fk blocks [0,FKB) + nlgemm blocks [FKB,FKB+NLB)
// R25: FK tile 64 -> 48 rows. LDS 65 -> 49 KB => 3 blocks/CU (24 waves/CU,
// +50% latency hiding on the dominant kernel). Each output row still computed
// by exactly one block with the identical k-order -> bit-identical outputs.
#define FK_MT 48
__global__ __launch_bounds__(512, 4) void k_gemms(const float* __restrict__ hsrc,
        const float* __restrict__ x, const float* __restrict__ nw, const float* __restrict__ nbv,
        const double* __restrict__ bnst, const float* __restrict__ bng, const float* __restrict__ bnb,
        int mode,
        const _Float16* __restrict__ whi, const _Float16* __restrict__ wlo,
        float* __restrict__ q0, float* __restrict__ q1,
        float* __restrict__ p2, float* __restrict__ p3,
        const _Float16* __restrict__ lwhi, const _Float16* __restrict__ lwlo,
        const float* __restrict__ linb,
        const float* __restrict__ attw, const float* __restrict__ attb,
        float* __restrict__ A1, float* __restrict__ A2,
        float* __restrict__ a1, float* __restrict__ a2,
        int FKB, int N) {
    __shared__ _Float16 ahi[FK_MT * 256];
    __shared__ _Float16 alo[FK_MT * 256];
    __shared__ float s_sc[128], s_sh[128];
    int tid = threadIdx.x;
    if (mode == 1) {
        if (tid < 128) {
            double invN = 1.0 / (double)N;
            float mu = (float)(bnst[tid] * invN);
            float var = (float)(bnst[128 + tid] * invN) - mu * mu;
            float inv = 1.f / sqrtf(var + 1e-5f);
            float sc = bng[tid] * inv;
            s_sc[tid] = sc;
            s_sh[tid] = bnb[tid] - mu * sc;
        }
        __syncthreads();
    }
    if (blockIdx.x < (unsigned)FKB) {
        // ---------------- FK body (R12 MFMA core, 48-row tile)
        int bx = blockIdx.x;
        int nb = (bx >> 2) * FK_MT;
        int ks = bx & 3;
        int kbase = ks * 256;
        int fr0 = kbase >> 7;
        {
            int row = tid >> 3;          // 0..63; rows >= FK_MT idle in staging
            int o8 = tid & 7;
            if (row < FK_MT) {
                int gn = nb + row;
                int rc = (gn < N) ? gn : (N - 1);
                float hv[2][8];
                if (mode == 0) {
                    float4 xr = *(const float4*)&x[(size_t)rc * 4];
#pragma unroll
                    for (int s = 0; s < 2; ++s)
#pragma unroll
                        for (int j = 0; j < 8; ++j) {
                            int c = s * 64 + o8 * 8 + j;
                            hv[s][j] = nbv[c] + xr.x * nw[c] + xr.y * nw[HID + c]
                                      + xr.z * nw[2 * HID + c] + xr.w * nw[3 * HID + c];
                        }
                } else {
                    const float* hp = hsrc + (size_t)rc * HID + o8 * 8;
                    *(float4*)&hv[0][0] = *(const float4*)hp;
                    *(float4*)&hv[0][4] = *(const float4*)(hp + 4);
                    *(float4*)&hv[1][0] = *(const float4*)(hp + 64);
                    *(float4*)&hv[1][4] = *(const float4*)(hp + 68);
#pragma unroll
                    for (int s = 0; s < 2; ++s)
#pragma unroll
                        for (int j = 0; j < 8; ++j) {
                            int c = s * 64 + o8 * 8 + j;
                            hv[s][j] = fmaxf(hv[s][j] * s_sc[c] + s_sh[c], 0.f);
                        }
                }
                int rs = row & 7;
#pragma unroll
                for (int g = 0; g < 2; ++g) {
                    float freqf = 6.2831853f * (float)(fr0 + g + 1);
#pragma unroll
                    for (int s = 0; s < 2; ++s) {
                        half8 vh, vl;
#pragma unroll
                        for (int j = 0; j < 8; ++j) {
                            float ang = freqf * hv[s][j] + 0.78539816f;
                            float a = 1.41421356f * __sinf(ang);
                            _Float16 hi = (_Float16)a;
                            vh[j] = hi;
                            vl[j] = (_Float16)((a - (float)hi) * 2048.f);
                        }
                        int oct = (g * 16 + s * 8 + o8) ^ rs;   // XOR bank swizzle
                        *(half8*)&ahi[row * 256 + oct * 8] = vh;
                        *(half8*)&alo[row * 256 + oct * 8] = vl;
                    }
                }
            }
        }
        __syncthreads();
        int lane = tid & 63, wv = tid >> 6;
        int quad = lane >> 4, l16 = lane & 15;
        int n0w = wv * 16;
        f4 acc0[3], accL[3];
#pragma unroll
        for (int mi = 0; mi < 3; ++mi) { acc0[mi] = (f4)(0.f); accL[mi] = (f4)(0.f); }
        const _Float16* bhp = whi + (size_t)(n0w + l16) * 1024 + kbase + quad * 8;
        const _Float16* blp = wlo + (size_t)(n0w + l16) * 1024 + kbase + quad * 8;
        int rs16 = (l16 & 7) << 3;
#pragma unroll 2
        for (int step = 0; step < 8; ++step) {
            int ka = (step * 32 + quad * 8) ^ rs16;
            int ko = step * 32;
            half8 bh = *(const half8*)(bhp + ko);
            half8 bl = *(const half8*)(blp + ko);
            half8 ah[3], al[3];
#pragma unroll
            for (int mi = 0; mi < 3; ++mi) {
                ah[mi] = *(const half8*)&ahi[(l16 + mi * 16) * 256 + ka];
                al[mi] = *(const half8*)&alo[(l16 + mi * 16) * 256 + ka];
            }
#pragma unroll
            for (int mi = 0; mi < 3; ++mi) {
                acc0[mi] = __builtin_amdgcn_mfma_f32_16x16x32_f16(ah[mi], bh, acc0[mi], 0, 0, 0);
                accL[mi] = __builtin_amdgcn_mfma_f32_16x16x32_f16(ah[mi], bl, accL[mi], 0, 0, 0);
                accL[mi] = __builtin_amdgcn_mfma_f32_16x16x32_f16(al[mi], bh, accL[mi], 0, 0, 0);
            }
        }
        float* p = (ks == 0) ? q0 : (ks == 1) ? q1 : (ks == 2) ? p2 : p3;
        const float inv = 1.0f / 2048.0f;
#pragma unroll
        for (int mi = 0; mi < 3; ++mi)
#pragma unroll
            for (int r = 0; r < 4; ++r) {
                int gn = nb + mi * 16 + quad * 4 + r;
                if (gn < N)
                    p[gn * HID + n0w + l16] = acc0[mi][r] + accL[mi][r] * inv;
            }
    } else {
        // ---------------- nlgemm body (R19 verbatim; uses prefix of ahi/alo)
        int nb = (blockIdx.x - FKB) * 32;
        {
            int row = tid >> 4;          // 0..31
            int o16 = tid & 15;
            int gn = nb + row;
            int rc = (gn < N) ? gn : (N - 1);
            float hv[8];
            if (mode == 0) {
                float4 xr = *(const float4*)&x[(size_t)rc * 4];
#pragma unroll
                for (int j = 0; j < 8; ++j) {
                    int c = o16 * 8 + j;
                    hv[j] = nbv[c] + xr.x * nw[c] + xr.y * nw[HID + c]
                           + xr.z * nw[2 * HID + c] + xr.w * nw[3 * HID + c];
                }
            } else {
                const float* hp = hsrc + (size_t)rc * HID + o16 * 8;
                *(float4*)&hv[0] = *(const float4*)hp;
                *(float4*)&hv[4] = *(const float4*)(hp + 4);
#pragma unroll
                for (int j = 0; j < 8; ++j) {
                    int c = o16 * 8 + j;
                    hv[j] = fmaxf(hv[j] * s_sc[c] + s_sh[c], 0.f);
                }
            }
            float p1 = 0.f, p2d = 0.f;
#pragma unroll
            for (int j = 0; j < 8; ++j) {
                int k = o16 * 8 + j;
                p1 += hv[j] * attw[k];
                p2d += hv[j] * attw[128 + k];
            }
            for (int off = 8; off > 0; off >>= 1) {
                p1 += __shfl_down(p1, off, 16);
                p2d += __shfl_down(p2d, off, 16);
            }
            if (o16 == 0 && gn < N) {
                a1[gn] = p1 + attb[0];
                a2[gn] = p2d;
            }
            int rs = row & 7;
            half8 vh, vl;
#pragma unroll
            for (int j = 0; j < 8; ++j) {
                float a = hv[j];
                _Float16 hi = (_Float16)a;
                vh[j] = hi;
                vl[j] = (_Float16)((a - (float)hi) * 2048.f);
            }
            int oct = o16 ^ rs;
            *(half8*)&ahi[row * 128 + oct * 8] = vh;
            *(half8*)&alo[row * 128 + oct * 8] = vl;
        }
        __syncthreads();
        int lane = tid & 63, wv = tid >> 6;
        int quad = lane >> 4, l16 = lane & 15;
        int n0 = wv * 32;
        f4 acc0[2][2], accL[2][2];
#pragma unroll
        for (int mi = 0; mi < 2; ++mi)
#pragma unroll
            for (int ni = 0; ni < 2; ++ni) { acc0[mi][ni] = (f4)(0.f); accL[mi][ni] = (f4)(0.f); }
        const _Float16* bhp0 = lwhi + (size_t)(n0 + l16) * 128 + quad * 8;
        const _Float16* bhp1 = lwhi + (size_t)(n0 + 16 + l16) * 128 + quad * 8;
        const _Float16* blp0 = lwlo + (size_t)(n0 + l16) * 128 + quad * 8;
        const _Float16* blp1 = lwlo + (size_t)(n0 + 16 + l16) * 128 + quad * 8;
        int rs16 = (l16 & 7) << 3;
#pragma unroll
        for (int step = 0; step < 4; ++step) {
            int ka = (step * 32 + quad * 8) ^ rs16;
            int ko = step * 32;
            half8 bh0 = *(const half8*)(bhp0 + ko);
            half8 bh1 = *(const half8*)(bhp1 + ko);
            half8 bl0 = *(const half8*)(blp0 + ko);
            half8 bl1 = *(const half8*)(blp1 + ko);
            half8 ah[2], al[2];
#pragma unroll
            for (int mi = 0; mi < 2; ++mi) {
                ah[mi] = *(const half8*)&ahi[(l16 + mi * 16) * 128 + ka];
                al[mi] = *(const half8*)&alo[(l16 + mi * 16) * 128 + ka];
            }
#pragma unroll
            for (int mi = 0; mi < 2; ++mi) {
                acc0[mi][0] = __builtin_amdgcn_mfma_f32_16x16x32_f16(ah[mi], bh0, acc0[mi][0], 0, 0, 0);
                acc0[mi][1] = __builtin_amdgcn_mfma_f32_16x16x32_f16(ah[mi], bh1, acc0[mi][1], 0, 0, 0);
                accL[mi][0] = __builtin_amdgcn_mfma_f32_16x16x32_f16(ah[mi], bl0, accL[mi][0], 0, 0, 0);
                accL[mi][1] = __builtin_amdgcn_mfma_f32_16x16x32_f16(ah[mi], bl1, accL[mi][1], 0, 0, 0);
                accL[mi][0] = __builtin_amdgcn_mfma_f32_16x16x32_f16(al[mi], bh0, accL[mi][0], 0, 0, 0);
                accL[mi][1] = __builtin_amdgcn_mfma_f32_16x16x32_f16(al[mi], bh1, accL[mi][1], 0, 0, 0);
            }
        }
        const float inv = 1.0f / 2048.0f;
#pragma unroll
        for (int mi = 0; mi < 2; ++mi)
#pragma unroll
            for (int ni = 0; ni < 2; ++ni)
#pragma unroll
                for (int r = 0; r < 4; ++r) {
                    int gn = nb + mi * 16 + quad * 4 + r;
                    if (gn >= N) continue;
                    int cp = n0 + ni * 16 + l16;
                    float val = acc0[mi][ni][r] + accL[mi][ni][r] * inv;
                    if (cp < 128) A1[(size_t)gn * HID + cp] = val + linb[cp];
                    else          A2[(size_t)gn * HID + cp - 128] = val;
                }
    }
}

// ---------------------------------------------------------------- edge conv (CSR)
// R24 k_edge verbatim: 4 nodes x 2 slots x 32 lanes, fused FK-partial + bias
// sum, index/attr software prefetch.
__global__ __launch_bounds__(256) void k_edge(const float* __restrict__ A1,
        const float* __restrict__ A2, const float* __restrict__ a1,
        const float* __restrict__ a2, const int* __restrict__ srco,
        const float4* __restrict__ ea3o, const int* __restrict__ offs,
        const float* __restrict__ linw3, const float* __restrict__ attw3,
        const float* __restrict__ q0, const float* __restrict__ q1,
        const float* __restrict__ p2s, const float* __restrict__ p3s,
        const float* __restrict__ fkb,
        float* __restrict__ hsum, int N) {
    __shared__ float part[4][HID + 4];
    int tid = threadIdx.x;
    int nl = tid >> 6;               // node-local 0..3
    int slot = (tid >> 5) & 1;       // 2 slots
    int lane32 = tid & 31;
    int n = blockIdx.x * 4 + nl;
    int c4 = lane32 * 4;
    float4 w0v = *(const float4*)&linw3[c4];
    float4 w1v = *(const float4*)&linw3[HID + c4];
    float4 w2v = *(const float4*)&linw3[2 * HID + c4];
    float aw0 = attw3[0], aw1 = attw3[1], aw2 = attw3[2];
    float a1n = 0.f;
    float4 A1v; A1v.x = A1v.y = A1v.z = A1v.w = 0.f;
    int s0 = 0, s1 = 0;
    if (n < N) {
        a1n = a1[n];
        A1v = *(const float4*)&A1[(size_t)n * HID + c4];
        s0 = offs[n]; s1 = offs[n + 1];
    }
    float4 acc; acc.x = acc.y = acc.z = acc.w = 0.f;
    int idx = s0 + slot;
    if (idx < s1) {
        int s = srco[idx];
        float4 q = ea3o[idx];
        float a2s = a2[s];
        while (1) {
            int idx2 = idx + 2;
            int sn = 0; float4 qn; float a2n = 0.f;
            int more = idx2 < s1;
            if (more) {                      // prefetch next edge's index/attr/a2
                sn = srco[idx2];
                qn = ea3o[idx2];
                a2n = a2[sn];
            }
            float logit = a1n + a2s + q.x * aw0 + q.y * aw1 + q.z * aw2;
            float al = 1.f / (1.f + __expf(-logit));
            float4 a2v = *(const float4*)&A2[(size_t)s * HID + c4];
            float4 pre;
            pre.x = A1v.x + a2v.x + q.x * w0v.x + q.y * w1v.x + q.z * w2v.x;
            pre.y = A1v.y + a2v.y + q.x * w0v.y + q.y * w1v.y + q.z * w2v.y;
            pre.z = A1v.z + a2v.z + q.x * w0v.z + q.y * w1v.z + q.z * w2v.z;
            pre.w = A1v.w + a2v.w + q.x * w0v.w + q.y * w1v.w + q.z * w2v.w;
            acc.x += al * pre.x; acc.y += al * pre.y;
            acc.z += al * pre.z; acc.w += al * pre.w;
            if (!more) break;
            idx = idx2; s = sn; q = qn; a2s = a2n;
        }
    }
    if (slot == 1) *(float4*)&part[nl][c4] = acc;
    __syncthreads();
    if (slot == 0 && n < N) {
        float4 r = *(const float4*)&part[nl][c4];
        float4 p;
        p.x = acc.x + r.x; p.y = acc.y + r.y;
        p.z = acc.z + r.z; p.w = acc.w + r.w;
        size_t idx2 = (size_t)n * HID + c4;
        float4 b0 = *(const float4*)&q0[idx2];
        float4 b1 = *(const float4*)&q1[idx2];
        float4 b2 = *(const float4*)&p2s[idx2];
        float4 b3 = *(const float4*)&p3s[idx2];
        float4 bias = *(const float4*)&fkb[c4];
        p.x = p.x + b0.x + b1.x + b2.x + b3.x + bias.x;
        p.y = p.y + b0.y + b1.y + b2.y + b3.y + bias.y;
        p.z = p.z + b0.z + b1.z + b2.z + b3.z + bias.z;
        p.w = p.w + b0.w + b1.w + b2.w + b3.w + bias.w;
        *(float4*)&hsum[idx2] = p;
    }
}

// ---------------------------------------------------------------- batchnorm stats (single stream)
__global__ __launch_bounds__(256) void k_bn_stats(const float* __restrict__ hsum,
                           double* __restrict__ stats, int N) {
    int tid = threadIdx.x;
    int cq = tid & 31, rg = tid >> 5;
    int c4 = cq * 4;
    float s1[4] = {0, 0, 0, 0}, s2[4] = {0, 0, 0, 0};
    for (int n = blockIdx.x * 8 + rg; n < N; n += gridDim.x * 8) {
        float4 v = *(const float4*)&hsum[(size_t)n * HID + c4];
        s1[0] += v.x; s2[0] += v.x * v.x;
        s1[1] += v.y; s2[1] += v.y * v.y;
        s1[2] += v.z; s2[2] += v.z * v.z;
        s1[3] += v.w; s2[3] += v.w * v.w;
    }
#pragma unroll
    for (int j = 0; j < 4; ++j) {
        s1[j] += __shfl_down(s1[j], 32);
        s2[j] += __shfl_down(s2[j], 32);
    }
    __shared__ float sh1[4][32][4], sh2[4][32][4];
    int wv = tid >> 6, lane = tid & 63;
    if (lane < 32) {
#pragma unroll
        for (int j = 0; j < 4; ++j) { sh1[wv][lane][j] = s1[j]; sh2[wv][lane][j] = s2[j]; }
    }
    __syncthreads();
    if (tid < 128) {
        int cq2 = tid >> 2, j2 = tid & 3;
        float t1 = sh1[0][cq2][j2] + sh1[1][cq2][j2] + sh1[2][cq2][j2] + sh1[3][cq2][j2];
        float t2 = sh2[0][cq2][j2] + sh2[1][cq2][j2] + sh2[2][cq2][j2] + sh2[3][cq2][j2];
        int c = cq2 * 4 + j2;
        atomicAdd(&stats[c], (double)t1);
        atomicAdd(&stats[128 + c], (double)t2);
    }
}

// bn_final folded in; float4 per thread; pool scores (last layer only)
__global__ void k_bn_apply(const float* __restrict__ hsum, const double* __restrict__ stats,
                           const float* __restrict__ g, const float* __restrict__ b,
                           const float* __restrict__ pw, const float* __restrict__ pb,
                           float* __restrict__ h, float* __restrict__ s,
                           int do_score, int N) {
    int idx = blockIdx.x * 256 + threadIdx.x;
    int row = idx >> 5, cq = idx & 31;
    int c4 = cq * 4;
    int valid = row < N;
    double invN = 1.0 / (double)N;
    float p = 0.f;
    if (valid) {
        float4 hv = *(const float4*)&hsum[(size_t)row * HID + c4];
        float vin[4] = {hv.x, hv.y, hv.z, hv.w};
        float4 ov;
        float* po = &ov.x;
#pragma unroll
        for (int j = 0; j < 4; ++j) {
            int c = c4 + j;
            float mu = (float)(stats[c] * invN);
            float var = (float)(stats[128 + c] * invN) - mu * mu;
            float inv = 1.f / sqrtf(var + 1e-5f);
            float sc = g[c] * inv;
            float sh = b[c] - mu * sc;
            float oo = fmaxf(vin[j] * sc + sh, 0.f);
            po[j] = oo;
            if (do_score) p += oo * pw[c];
        }
        *(float4*)&h[(size_t)row * HID + c4] = ov;
    }
    if (do_score) {
        for (int off = 16; off > 0; off >>= 1) p += __shfl_down(p, off, 32);
        if ((threadIdx.x & 31) == 0 && valid) s[row] = p + pb[0];
    }
}

// ---------------------------------------------------------------- softmax partials
__global__ void k_smax1(const float* __restrict__ s, float* __restrict__ mzp, int N) {
    __shared__ float red[256];
    float m = -INFINITY;
    for (int n = blockIdx.x * 256 + threadIdx.x; n < N; n += SMAXB * 256)
        m = fmaxf(m, s[n]);
    red[threadIdx.x] = m;
    __syncthreads();
    for (int off = 128; off > 0; off >>= 1) {
        if (threadIdx.x < (unsigned)off)
            red[threadIdx.x] = fmaxf(red[threadIdx.x], red[threadIdx.x + off]);
        __syncthreads();
    }
    m = red[0];
    __syncthreads();
    float z = 0.f;
    for (int n = blockIdx.x * 256 + threadIdx.x; n < N; n += SMAXB * 256)
        z += __expf(s[n] - m);
    red[threadIdx.x] = z;
    __syncthreads();
    for (int off = 128; off > 0; off >>= 1) {
        if (threadIdx.x < (unsigned)off) red[threadIdx.x] += red[threadIdx.x + off];
        __syncthreads();
    }
    if (threadIdx.x == 0) { mzp[blockIdx.x * 2] = m; mzp[blockIdx.x * 2 + 1] = red[0]; }
}

__device__ __forceinline__ void combine_mz(const float* mzp, float& m, float& Z) {
    m = -INFINITY;
#pragma unroll 8
    for (int i = 0; i < SMAXB; ++i) m = fmaxf(m, mzp[i * 2]);
    Z = 0.f;
#pragma unroll 8
    for (int i = 0; i < SMAXB; ++i) Z += mzp[i * 2 + 1] * __expf(mzp[i * 2] - m);
}

// ---------------------------------------------------------------- attention pool (split)
__global__ void k_pool_part(const float* __restrict__ h, const float* __restrict__ s,
                            const float* __restrict__ mzp, const int* __restrict__ boffs,
                            float* __restrict__ part) {
    int b = blockIdx.x >> 4, split = blockIdx.x & (PSPLIT - 1);
    int c = threadIdx.x & 127, half = threadIdx.x >> 7;
    float m, Z;
    combine_mz(mzp, m, Z);
    (void)Z;
    int n0 = boffs[b], n1 = boffs[b + 1];
    float acc = 0.f;
    for (int n = n0 + split * 2 + half; n < n1; n += PSPLIT * 2)
        acc += __expf(s[n] - m) * h[n * HID + c];
    __shared__ float prt[2][HID];
    prt[half][c] = acc;
    __syncthreads();
    if (half == 0) part[(size_t)(b * PSPLIT + split) * HID + c] = prt[0][c] + prt[1][c];
}

// ---------------------------------------------------------------- heads (grid = B*4; pooled computed inline from part)
__global__ __launch_bounds__(256) void k_head(const float* __restrict__ part,
                       const float* __restrict__ mzp,
                       const float* __restrict__ sg_table,
                       const int* __restrict__ space_group,
                       const float* __restrict__ hw1, const float* __restrict__ hb1,
                       const float* __restrict__ ew2, const float* __restrict__ eb2,
                       const float* __restrict__ sw2, const float* __restrict__ sb2,
                       const float* __restrict__ cw2, const float* __restrict__ cb2,
                       const float* __restrict__ mw2, const float* __restrict__ mb2,
                       float* __restrict__ out, int B) {
    __shared__ float comb[256];
    __shared__ float zred[2][128];
    __shared__ float zsh[128];
    int b = blockIdx.x >> 2, i = blockIdx.x & 3;
    int t = threadIdx.x;
    if (t < 128) {
        float m, Z;
        combine_mz(mzp, m, Z);
        float acc = 0.f;
#pragma unroll
        for (int j = 0; j < PSPLIT; ++j) acc += part[(size_t)(b * PSPLIT + j) * HID + t];
        comb[t] = acc / Z;
    } else {
        comb[t] = sg_table[space_group[b] * HID + (t - 128)];
    }
    __syncthreads();
    int half = t >> 7, tt = t & 127;
    const float* W = hw1 + ((size_t)i * 256 + half * 128) * HID;
    const float* cb = &comb[half * 128];
    float z = 0.f;
#pragma unroll 8
    for (int k = 0; k < 128; ++k) z += cb[k] * W[k * HID + tt];
    zred[half][tt] = z;
    __syncthreads();
    if (t < 128) zsh[t] = fmaxf(zred[0][t] + zred[1][t] + hb1[i * HID + t], 0.f);
    __syncthreads();
    const int od[4] = {1, 3, 7, 3};
    const int base[4] = {0, 64, 256, 704};
    const float* w2 = (i == 0) ? ew2 : (i == 1) ? sw2 : (i == 2) ? cw2 : mw2;
    const float* b2 = (i == 0) ? eb2 : (i == 1) ? sb2 : (i == 2) ? cb2 : mb2;
    int odi = od[i];
    if (t < odi) {
        float o = b2[t];
        for (int c = 0; c < HID; ++c) o += zsh[c] * w2[c * odi + t];
        out[base[i] + b * odi + t] = o;
    }
}

// ---------------------------------------------------------------- launch
extern "C" void kernel_launch(void* const* d_in, const int* in_sizes, int n_in,
                              void* d_out, int out_size, void* d_ws, size_t ws_size,
                              hipStream_t stream) {
    const float* x          = (const float*)d_in[0];
    const int*   edge_index = (const int*)d_in[1];
    const float* edge_attr  = (const float*)d_in[2];
    const int*   batch      = (const int*)d_in[3];
    const int*   space_group= (const int*)d_in[4];
    const float* node_w     = (const float*)d_in[5];
    const float* node_b     = (const float*)d_in[6];
    const float* sg_table   = (const float*)d_in[7];
    const float* lin_w      = (const float*)d_in[8];
    const float* lin_b      = (const float*)d_in[9];
    const float* att_w      = (const float*)d_in[10];
    const float* att_b      = (const float*)d_in[11];
    const float* fk_w       = (const float*)d_in[12];
    const float* fk_b       = (const float*)d_in[13];
    const float* bn_g       = (const float*)d_in[14];
    const float* bn_b       = (const float*)d_in[15];
    const float* pool_w     = (const float*)d_in[16];
    const float* pool_b     = (const float*)d_in[17];
    const float* head_w1    = (const float*)d_in[18];
    const float* head_b1    = (const float*)d_in[19];
    const float* ew2 = (const float*)d_in[20]; const float* eb2 = (const float*)d_in[21];
    const float* sw2 = (const float*)d_in[22]; const float* sb2 = (const float*)d_in[23];
    const float* cw2 = (const float*)d_in[24]; const float* cb2 = (const float*)d_in[25];
    const float* mw2 = (const float*)d_in[26]; const float* mb2 = (const float*)d_in[27];
    float* out = (float*)d_out;

    const int N = in_sizes[3];
    const int E = in_sizes[1] / 2;
    const int B = in_sizes[4];
    const int* src = edge_index;
    const int* dst = edge_index + E;

    char* w = (char*)d_ws;
    auto alloc = [&](size_t bytes) { char* p = w; w += (bytes + 255) & ~(size_t)255; return p; };
    float*  h      = (float*)alloc((size_t)N * HID * 4);   // final BN'd h (layer 3)
    float*  A1     = (float*)alloc((size_t)N * HID * 4);   // nlgemm out d-half
    float*  A2     = (float*)alloc((size_t)N * HID * 4);   // nlgemm out s-half
    float*  q0     = (float*)alloc((size_t)N * HID * 4);   // FK partial 0
    float*  q1     = (float*)alloc((size_t)N * HID * 4);   // FK partial 1
    float*  p2     = (float*)alloc((size_t)N * HID * 4);   // FK partial 2
    float*  p3     = (float*)alloc((size_t)N * HID * 4);   // FK partial 3
    float*  hcv0   = (float*)alloc((size_t)N * HID * 4);   // pre-BN sum ping
    float*  hcv1   = (float*)alloc((size_t)N * HID * 4);   // pre-BN sum pong
    float*  a1     = (float*)alloc((size_t)N * 4);
    float*  a2     = (float*)alloc((size_t)N * 4);
    float*  sbuf   = (float*)alloc((size_t)N * 4);
    int*    deg    = (int*)alloc((size_t)N * 4);
    int*    cursor = (int*)alloc((size_t)N * 4);
    int*    offs   = (int*)alloc((size_t)(N + 1) * 4);
    int*    srco   = (int*)alloc((size_t)E * 4);
    float4* ea3o   = (float4*)alloc((size_t)E * 16);
    _Float16* whi  = (_Float16*)alloc((size_t)DEPTH * 1024 * HID * 2);
    _Float16* wlo  = (_Float16*)alloc((size_t)DEPTH * 1024 * HID * 2);
    _Float16* lwhi = (_Float16*)alloc((size_t)DEPTH * 256 * HID * 2);
    _Float16* lwlo = (_Float16*)alloc((size_t)DEPTH * 256 * HID * 2);
    int*    bsum   = (int*)alloc(256 * 4);
    int*    boffs  = (int*)alloc((size_t)(B + 1) * 4);
    double* stats  = (double*)alloc((size_t)DEPTH * 256 * 8);
    float*  mzp    = (float*)alloc(SMAXB * 2 * 4);
    float*  part   = (float*)alloc((size_t)B * PSPLIT * HID * 4);

    const int nchunk = (N + 255) / 256;
    const int echunk = (E + 255) / 256;
    const int FKB = ((N + FK_MT - 1) / FK_MT) * 4;
    const int NLB = (N + 31) / 32;

    // one-time per launch: W splits + CSR build + stats zero
    k_wsplit<<<128, 256, 0, stream>>>(fk_w, whi, wlo);
    k_wsplit2<<<32, 256, 0, stream>>>(lin_w, lwhi, lwlo);
    hipMemsetAsync(deg, 0, (size_t)N * 4, stream);
    hipMemsetAsync(stats, 0, (size_t)DEPTH * 256 * 8, stream);
    k_hist<<<echunk, 256, 0, stream>>>(dst, deg, E);
    k_scan_a<<<nchunk, 256, 0, stream>>>(deg, bsum, N);
    k_scan_b<<<1, 256, 0, stream>>>(bsum, nchunk);
    k_scan_c<<<nchunk, 256, 0, stream>>>(deg, bsum, offs, cursor, N);
    k_scatter<<<echunk, 256, 0, stream>>>(src, dst, edge_attr, cursor, srco, ea3o, E);
    k_bstart<<<nchunk, 256, 0, stream>>>(batch, boffs, N, B);

    float* hcv[2] = {hcv0, hcv1};
    for (int l = 0; l < DEPTH; ++l) {
        const float* linw_l = lin_w + (size_t)l * 259 * HID;
        int mode = (l == 0) ? 0 : 1;
        const double* bst = (l == 0) ? (const double*)nullptr : stats + (size_t)(l - 1) * 256;
        const float* bgl = bn_g + (size_t)((l == 0) ? 0 : (l - 1)) * HID;
        const float* bbl = bn_b + (size_t)((l == 0) ? 0 : (l - 1)) * HID;
        const float* hprev = (l == 0) ? h : hcv[(l - 1) & 1];
        float* hcur = hcv[l & 1];
        k_gemms<<<FKB + NLB, 512, 0, stream>>>(
            hprev, x, node_w, node_b, bst, bgl, bbl, mode,
            whi + (size_t)l * 131072, wlo + (size_t)l * 131072, q0, q1, p2, p3,
            lwhi + (size_t)l * 32768, lwlo + (size_t)l * 32768,
            lin_b + l * HID, att_w + (size_t)l * 259, att_b + l,
            A1, A2, a1, a2, FKB, N);
        k_edge<<<(N + 3) / 4, 256, 0, stream>>>(A1, A2, a1, a2, srco, ea3o, offs,
                                      linw_l + 256 * HID, att_w + (size_t)l * 259 + 256,
                                      q0, q1, p2, p3, fk_b + l * HID,
                                      hcur, N);
        k_bn_stats<<<320, 256, 0, stream>>>(hcur, stats + (size_t)l * 256, N);
    }
    // final BN + pool scores from layer-3 pre-BN sum
    k_bn_apply<<<(N * 32 + 255) / 256, 256, 0, stream>>>(
        hcv[(DEPTH - 1) & 1], stats + (size_t)(DEPTH - 1) * 256,
        bn_g + (size_t)(DEPTH - 1) * HID, bn_b + (size_t)(DEPTH - 1) * HID,
        pool_w, pool_b, h, sbuf, 1, N);

    k_smax1<<<SMAXB, 256, 0, stream>>>(sbuf, mzp, N);
    k_pool_part<<<B * PSPLIT, 256, 0, stream>>>(h, sbuf, mzp, boffs, part);
    k_head<<<B * 4, 256, 0, stream>>>(part, mzp, sg_table, space_group, head_w1, head_b1,
                                      ew2, eb2, sw2, sb2, cw2, cb2, mw2, mb2, out, B);
}